// Round 6
// baseline (579.979 us; speedup 1.0000x reference)
//
#include <hip/hip_runtime.h>
#include <hip/hip_bf16.h>

// Shapes (fixed): B=4, H=56, W=56, C=256, NH=8, HD=32, KS=7, PAD=3
// tokens M = 4*56*56 = 12544. Padded k/v planes: [4][64][64][256] bf16,
// interior token (y,x) at plane row y+3, col x+3; border zeroed by prep.

using frag_ab = __attribute__((ext_vector_type(8))) short;  // 8 bf16 (4 VGPRs)
using f32x4   = __attribute__((ext_vector_type(4))) float;  // 4 fp32 acc

typedef const __attribute__((address_space(1))) unsigned int* gas_u32;
typedef __attribute__((address_space(3))) unsigned int*       las_u32;

__device__ __forceinline__ void gl_lds16(const void* g, void* l) {
    // async global->LDS DMA, 16 B/lane; LDS dst = wave-uniform base + lane*16
    __builtin_amdgcn_global_load_lds((gas_u32)g, (las_u32)l, 16, 0, 0);
}

__device__ __forceinline__ float bflo(unsigned int u) { return __uint_as_float(u << 16); }
__device__ __forceinline__ float bfhi(unsigned int u) { return __uint_as_float(u & 0xffff0000u); }

// ================= fused prep =================
// blocks [0,3136):    x fp32 -> xb bf16 (float4/thread)
// blocks [3136,3904): w_qkv [256][768] -> wqkvT [768][256] bf16
// blocks [3904,4160): w_proj [256][256] -> wprojT [256][256] bf16
// blocks [4160,5120): zero the 960 border cols of each padded plane
__global__ __launch_bounds__(256) void prep(
    const float* __restrict__ x,      __hip_bfloat16* __restrict__ xb,
    const float* __restrict__ w_qkv,  __hip_bfloat16* __restrict__ wqkvT,
    const float* __restrict__ w_proj, __hip_bfloat16* __restrict__ wprojT,
    __hip_bfloat16* __restrict__ kp,  __hip_bfloat16* __restrict__ vp)
{
    const int bid = blockIdx.x;
    const int tid = threadIdx.x;
    if (bid < 3136) {
        const int i = bid * 256 + tid;            // over M*256/4 = 802816
        const float4 v = ((const float4*)x)[i];
        union { ushort4 u; __hip_bfloat16 h[4]; } o;
        o.h[0] = __float2bfloat16(v.x); o.h[1] = __float2bfloat16(v.y);
        o.h[2] = __float2bfloat16(v.z); o.h[3] = __float2bfloat16(v.w);
        ((ushort4*)xb)[i] = o.u;
    } else if (bid < 3904) {
        const int idx = (bid - 3136) * 256 + tid; // over 768*256
        const int k = idx & 255, n = idx >> 8;
        wqkvT[idx] = __float2bfloat16(w_qkv[k * 768 + n]);
    } else if (bid < 4160) {
        const int idx = (bid - 3904) * 256 + tid; // over 256*256
        const int k = idx & 255, n = idx >> 8;
        wprojT[idx] = __float2bfloat16(w_proj[k * 256 + n]);
    } else {
        const int u    = (bid - 4160) * 256 + tid;   // over 8*30720
        const int ip   = u / 30720;                  // img*2 + plane
        const int rem  = u - ip * 30720;
        const int cloc = rem >> 5;                   // 0..959 border cells
        const int q16  = rem & 31;                   // 16B chunk of 256 ch
        const int img  = ip >> 1;
        __hip_bfloat16* base = (ip & 1) ? vp : kp;
        int prow, pcol;
        if (cloc < 512) {                            // full pad rows 0-2,59-63
            const int r8 = cloc >> 6;
            prow = (r8 < 3) ? r8 : r8 + 56;
            pcol = cloc & 63;
        } else {                                     // side pads of rows 3..58
            const int c2 = cloc - 512;
            prow = 3 + (c2 >> 3);
            const int cc = c2 & 7;
            pcol = (cc < 3) ? cc : cc + 56;
        }
        *(uint4*)(base + (((size_t)(img * 64 + prow)) * 64 + pcol) * 256 + q16 * 8) =
            make_uint4(0u, 0u, 0u, 0u);
    }
}

// ================= 128x128 bf16 MFMA GEMM cores =================
// 256 thr = 4 waves; wave w owns quadrant (w>>1, w&1) as 4x4 16x16x32 frags.
// Staging in fragment order via global_load_lds: wave w DMAs A row-blocks
// 2w,2w+1 and B row-blocks 2w,2w+1 (block = 16 rows x 32 k = 64 lanes x 16 B).
#define GEMM128_BODY(EPILOGUE)                                                  \
    constexpr int K = 256;                                                      \
    __shared__ frag_ab As[8][64];   /* 8 KB */                                  \
    __shared__ frag_ab Bs[8][64];   /* 8 KB */                                  \
    const int tid  = threadIdx.x;                                               \
    const int lane = tid & 63;                                                  \
    const int w    = tid >> 6;                                                  \
    const int wm   = w >> 1, wn = w & 1;                                        \
    const int m0 = blockIdx.y * 128;                                            \
    const int n0 = blockIdx.x * 128;                                            \
    const int lrow = lane & 15;                                                 \
    const int lk   = (lane >> 4) * 8;                                           \
    const __hip_bfloat16* gA0 = A  + (size_t)(m0 + (2*w+0)*16 + lrow) * K + lk; \
    const __hip_bfloat16* gA1 = A  + (size_t)(m0 + (2*w+1)*16 + lrow) * K + lk; \
    const __hip_bfloat16* gB0 = BT + (size_t)(n0 + (2*w+0)*16 + lrow) * K + lk; \
    const __hip_bfloat16* gB1 = BT + (size_t)(n0 + (2*w+1)*16 + lrow) * K + lk; \
    f32x4 acc[4][4] = {};                                                       \
    for (int k0 = 0; k0 < K; k0 += 32) {                                        \
        gl_lds16(gA0 + k0, &As[2*w+0][0]);                                      \
        gl_lds16(gA1 + k0, &As[2*w+1][0]);                                      \
        gl_lds16(gB0 + k0, &Bs[2*w+0][0]);                                      \
        gl_lds16(gB1 + k0, &Bs[2*w+1][0]);                                      \
        __syncthreads();                                                        \
        frag_ab af[4], bf[4];                                                   \
        _Pragma("unroll")                                                       \
        for (int i = 0; i < 4; ++i) { af[i] = As[wm*4+i][lane]; bf[i] = Bs[wn*4+i][lane]; } \
        _Pragma("unroll")                                                       \
        for (int i = 0; i < 4; ++i)                                             \
            _Pragma("unroll")                                                   \
            for (int j = 0; j < 4; ++j)                                         \
                acc[i][j] = __builtin_amdgcn_mfma_f32_16x16x32_bf16(af[i], bf[j], acc[i][j], 0, 0, 0); \
        __syncthreads();                                                        \
    }                                                                           \
    const int rbase = (lane >> 4) * 4;                                          \
    const int cbase = lane & 15;                                                \
    _Pragma("unroll")                                                           \
    for (int fi = 0; fi < 4; ++fi) {                                            \
        const int rm = m0 + wm * 64 + fi * 16 + rbase;                          \
        _Pragma("unroll")                                                       \
        for (int fj = 0; fj < 4; ++fj) {                                        \
            const int cn = n0 + wn * 64 + fj * 16 + cbase;                      \
            const float bv = bias[cn];                                          \
            _Pragma("unroll")                                                   \
            for (int r = 0; r < 4; ++r) {                                       \
                const int m = rm + r;                                           \
                const float val = acc[fi][fj][r] + bv;                          \
                EPILOGUE                                                        \
            }                                                                   \
        }                                                                       \
    }

// QKV GEMM: N=768; cols 0-255 -> qf fp32 (scaled); 256-511 -> kp; 512-767 -> vp
__global__ __launch_bounds__(256) void gemm_qkv(
    const __hip_bfloat16* __restrict__ A,
    const __hip_bfloat16* __restrict__ BT,
    const float* __restrict__ bias,
    float* __restrict__ qf,
    __hip_bfloat16* __restrict__ kp,
    __hip_bfloat16* __restrict__ vp,
    float qscale)
{
    const int N = 768; (void)N;
    GEMM128_BODY({
        const int sel = cn >> 8;                       // 0=q,1=k,2=v (uniform/block)
        if (sel == 0) {
            qf[(size_t)m * 256 + cn] = val * qscale;
        } else {
            const int c  = cn & 255;
            const int b  = m / 3136;
            const int r2 = m % 3136;
            const int yy = r2 / 56;
            const int xx = r2 % 56;
            __hip_bfloat16* dst = (sel == 1) ? kp : vp;
            dst[(((size_t)(b * 64 + yy + 3)) * 64 + (xx + 3)) * 256 + c] =
                __float2bfloat16(val);
        }
    })
}

// proj GEMM: C fp32 [M][256] = A bf16 @ BT bf16 + bias
__global__ __launch_bounds__(256) void gemm_proj(
    const __hip_bfloat16* __restrict__ A,
    const __hip_bfloat16* __restrict__ BT,
    const float* __restrict__ bias,
    float* __restrict__ C)
{
    GEMM128_BODY({
        C[(size_t)m * 256 + cn] = val;
    })
}

// ================= neighborhood attention =================
// Block = 128 thr = 2 independent waves; wave = 4 tokens x 8 heads x 2 half-heads.
// Grid = 1568. Per ky the wave stages 10 cols x 256 ch bf16 (5 KB) of the padded
// k (then v) plane: 5x global_load_dwordx4 -> 5x ds_write_b128 into a padded
// LDS layout (col stride 264 halfwords = 528 B -> measured-conflict-free reads),
// register-double-buffered: loads for ky+1 in flight while computing ky.
// Zero-padded planes => branch-free; OOB logit = rpb (reference semantics).
__global__ __launch_bounds__(128, 3) void na2d_attn5(
    const float* __restrict__ qf,
    const __hip_bfloat16* __restrict__ kp,
    const __hip_bfloat16* __restrict__ vp,
    const float* __restrict__ rpb,
    __hip_bfloat16* __restrict__ out)
{
    const int tid  = threadIdx.x;
    const int wave = tid >> 6;
    const int lane = tid & 63;
    const int half = lane & 1;          // 16-ch half of a head
    const int h    = (lane >> 1) & 7;   // head
    const int tl   = (lane >> 4) & 3;   // token within wave's 4-token segment

    const int seg = blockIdx.x;         // 0..1567
    const int row = seg / 7;            // b*56 + y
    const int x0  = (seg % 7) * 8 + wave * 4;   // 0..52
    const int b   = row / 56;
    const int y   = row % 56;
    const int t   = row * 56 + x0 + tl;
    const int prow0 = b * 64 + y;       // padded plane row for ky=0

    __shared__ __hip_bfloat16 kbuf[2][2][10 * 264];   // [wave][parity] 20.6 KB
    __shared__ float srpb[8 * 49];

    for (int i = tid; i < 8 * 49; i += 128) srpb[i] = rpb[i];
    __syncthreads();                    // only barrier in the kernel

    // q: 16 fp32 channels (lanes of one token cover its 256 ch contiguously)
    float q[16];
    {
        const float4* qp = (const float4*)(qf + (size_t)t * 256 + h * 32 + half * 16);
        #pragma unroll
        for (int i = 0; i < 4; ++i) {
            const float4 v4 = qp[i];
            q[4 * i + 0] = v4.x; q[4 * i + 1] = v4.y;
            q[4 * i + 2] = v4.z; q[4 * i + 3] = v4.w;
        }
    }

    uint4 g[5];
    auto gload = [&](const __hip_bfloat16* plane, int ky) {
        const __hip_bfloat16* rb =
            plane + ((size_t)(prow0 + ky) * 64 + x0) * 256 + lane * 8;
        #pragma unroll
        for (int i = 0; i < 5; ++i) g[i] = *(const uint4*)(rb + i * 512);
    };
    auto lwrite = [&](int par) {
        char* base = (char*)&kbuf[wave][par][0];
        #pragma unroll
        for (int i = 0; i < 5; ++i) {
            const int unit = lane + i * 64;     // 0..319
            const int col  = unit >> 5;         // 0..9
            const int j    = unit & 31;         // 16B chunk
            *(uint4*)(base + col * 528 + j * 16) = g[i];
        }
    };

    float logit[49];

    // ---- QK phase ----
    gload(kp, 0);
    #pragma unroll
    for (int ky = 0; ky < 7; ++ky) {
        lwrite(ky & 1);
        if (ky < 6) gload(kp, ky + 1);          // next row in flight
        const char* kb = (const char*)&kbuf[wave][ky & 1][0];
        #pragma unroll
        for (int kx = 0; kx < 7; ++kx) {
            const uint4* p = (const uint4*)(kb + (tl + kx) * 528 + h * 64 + half * 32);
            float s = 0.f;
            #pragma unroll
            for (int qd = 0; qd < 2; ++qd) {
                const uint4 wv = p[qd];
                const int o8 = qd * 8;
                s += q[o8 + 0] * bflo(wv.x) + q[o8 + 1] * bfhi(wv.x)
                   + q[o8 + 2] * bflo(wv.y) + q[o8 + 3] * bfhi(wv.y)
                   + q[o8 + 4] * bflo(wv.z) + q[o8 + 5] * bfhi(wv.z)
                   + q[o8 + 6] * bflo(wv.w) + q[o8 + 7] * bfhi(wv.w);
            }
            logit[ky * 7 + kx] = s;
        }
    }

    // merge half-head partials (lane pairs differ only in `half`)
    #pragma unroll
    for (int kk = 0; kk < 49; ++kk)
        logit[kk] += __shfl_xor(logit[kk], 1, 64);

    // ---- softmax over 49 (+rpb; zero-pads give logit = rpb) ----
    const float* rp = &srpb[h * 49];
    float mx = -1e30f;
    #pragma unroll
    for (int kk = 0; kk < 49; ++kk) {
        logit[kk] += rp[kk];
        mx = fmaxf(mx, logit[kk]);
    }
    float ssum = 0.f;
    #pragma unroll
    for (int kk = 0; kk < 49; ++kk) {
        const float e = __expf(logit[kk] - mx);
        logit[kk] = e;
        ssum += e;
    }
    const float inv = 1.f / ssum;

    // ---- PV phase ----
    float o[16] = {};
    gload(vp, 0);
    #pragma unroll
    for (int ky = 0; ky < 7; ++ky) {
        lwrite(ky & 1);
        if (ky < 6) gload(vp, ky + 1);
        const char* vb = (const char*)&kbuf[wave][ky & 1][0];
        #pragma unroll
        for (int kx = 0; kx < 7; ++kx) {
            const float pr = logit[ky * 7 + kx];
            const uint4* p = (const uint4*)(vb + (tl + kx) * 528 + h * 64 + half * 32);
            #pragma unroll
            for (int qd = 0; qd < 2; ++qd) {
                const uint4 wv = p[qd];
                const int o8 = qd * 8;
                o[o8 + 0] += pr * bflo(wv.x); o[o8 + 1] += pr * bfhi(wv.x);
                o[o8 + 2] += pr * bflo(wv.y); o[o8 + 3] += pr * bfhi(wv.y);
                o[o8 + 4] += pr * bflo(wv.z); o[o8 + 5] += pr * bfhi(wv.z);
                o[o8 + 6] += pr * bflo(wv.w); o[o8 + 7] += pr * bfhi(wv.w);
            }
        }
    }

    // ---- store bf16 (feeds proj GEMM) ----
    union { uint4 u[2]; __hip_bfloat16 hh[16]; } ob;
    #pragma unroll
    for (int i = 0; i < 16; ++i) ob.hh[i] = __float2bfloat16(o[i] * inv);
    uint4* op = (uint4*)(out + (size_t)t * 256 + h * 32 + half * 16);
    op[0] = ob.u[0];
    op[1] = ob.u[1];
}

extern "C" void kernel_launch(void* const* d_in, const int* in_sizes, int n_in,
                              void* d_out, int out_size, void* d_ws, size_t ws_size,
                              hipStream_t stream)
{
    const float* x      = (const float*)d_in[0];   // (4,56,56,256)
    const float* w_qkv  = (const float*)d_in[1];   // (256,768)
    const float* b_qkv  = (const float*)d_in[2];   // (768,)
    const float* rpb    = (const float*)d_in[3];   // (8,49)
    const float* w_proj = (const float*)d_in[4];   // (256,256)
    const float* b_proj = (const float*)d_in[5];   // (256,)
    float* out = (float*)d_out;                    // (4,56,56,256) fp32

    const int M = 12544;

    char* wsp = (char*)d_ws;
    float* qf = (float*)wsp;                      wsp += (size_t)M * 256 * 4;   // 12.85 MB
    __hip_bfloat16* kp    = (__hip_bfloat16*)wsp; wsp += (size_t)4 * 64 * 64 * 256 * 2; // 8.39 MB
    __hip_bfloat16* vp    = (__hip_bfloat16*)wsp; wsp += (size_t)4 * 64 * 64 * 256 * 2; // 8.39 MB
    __hip_bfloat16* xb    = (__hip_bfloat16*)wsp; wsp += (size_t)M * 256 * 2;
    __hip_bfloat16* attnb = (__hip_bfloat16*)wsp; wsp += (size_t)M * 256 * 2;
    __hip_bfloat16* wqkvT = (__hip_bfloat16*)wsp; wsp += (size_t)768 * 256 * 2;
    __hip_bfloat16* wprojT= (__hip_bfloat16*)wsp; wsp += (size_t)256 * 256 * 2;

    const float scale = 0.17677669529663689f;  // 32^-0.5

    // fused prep: x->bf16, both weight transposes, pad-border zero of kp/vp
    prep<<<5120, 256, 0, stream>>>(x, xb, w_qkv, wqkvT, w_proj, wprojT, kp, vp);

    // qkv = xb @ wqkvT^T + b_qkv; q fp32 scaled -> qf; k/v bf16 -> padded planes
    gemm_qkv<<<dim3(6, 98), 256, 0, stream>>>(xb, wqkvT, b_qkv, qf, kp, vp, scale);

    // attention: 1568 blocks x 128 threads (2 independent waves x 4 tokens)
    na2d_attn5<<<1568, 128, 0, stream>>>(qf, kp, vp, rpb, attnb);

    // out = attnb @ wprojT^T + b_proj
    gemm_proj<<<dim3(2, 98), 256, 0, stream>>>(attnb, wprojT, b_proj, out);
}

// Round 7
// 364.965 us; speedup vs baseline: 1.5891x; 1.5891x over previous
//
#include <hip/hip_runtime.h>
#include <hip/hip_bf16.h>

// Shapes (fixed): B=4, H=56, W=56, C=256, NH=8, HD=32, KS=7, PAD=3
// tokens M = 4*56*56 = 12544. Padded k/v planes: [4][64][64][256] bf16,
// interior token (y,x) at plane row y+3, col x+3; border zeroed by prep.

using frag_ab = __attribute__((ext_vector_type(8))) short;  // 8 bf16 (4 VGPRs)
using f32x4   = __attribute__((ext_vector_type(4))) float;  // 4 fp32 acc

typedef const __attribute__((address_space(1))) unsigned int* gas_u32;
typedef __attribute__((address_space(3))) unsigned int*       las_u32;

__device__ __forceinline__ void gl_lds16(const void* g, void* l) {
    // async global->LDS DMA, 16 B/lane; LDS dst = wave-uniform base + lane*16
    __builtin_amdgcn_global_load_lds((gas_u32)g, (las_u32)l, 16, 0, 0);
}

__device__ __forceinline__ float bflo(unsigned int u) { return __uint_as_float(u << 16); }
__device__ __forceinline__ float bfhi(unsigned int u) { return __uint_as_float(u & 0xffff0000u); }

// ================= fused prep =================
// blocks [0,3136):    x fp32 -> xb bf16 (float4/thread)
// blocks [3136,3904): w_qkv [256][768] -> wqkvT [768][256] bf16
// blocks [3904,4160): w_proj [256][256] -> wprojT [256][256] bf16
// blocks [4160,5120): zero the 960 border cols of each padded plane
__global__ __launch_bounds__(256) void prep(
    const float* __restrict__ x,      __hip_bfloat16* __restrict__ xb,
    const float* __restrict__ w_qkv,  __hip_bfloat16* __restrict__ wqkvT,
    const float* __restrict__ w_proj, __hip_bfloat16* __restrict__ wprojT,
    __hip_bfloat16* __restrict__ kp,  __hip_bfloat16* __restrict__ vp)
{
    const int bid = blockIdx.x;
    const int tid = threadIdx.x;
    if (bid < 3136) {
        const int i = bid * 256 + tid;            // over M*256/4 = 802816
        const float4 v = ((const float4*)x)[i];
        union { ushort4 u; __hip_bfloat16 h[4]; } o;
        o.h[0] = __float2bfloat16(v.x); o.h[1] = __float2bfloat16(v.y);
        o.h[2] = __float2bfloat16(v.z); o.h[3] = __float2bfloat16(v.w);
        ((ushort4*)xb)[i] = o.u;
    } else if (bid < 3904) {
        const int idx = (bid - 3136) * 256 + tid; // over 768*256
        const int k = idx & 255, n = idx >> 8;
        wqkvT[idx] = __float2bfloat16(w_qkv[k * 768 + n]);
    } else if (bid < 4160) {
        const int idx = (bid - 3904) * 256 + tid; // over 256*256
        const int k = idx & 255, n = idx >> 8;
        wprojT[idx] = __float2bfloat16(w_proj[k * 256 + n]);
    } else {
        const int u    = (bid - 4160) * 256 + tid;   // over 8*30720
        const int ip   = u / 30720;                  // img*2 + plane
        const int rem  = u - ip * 30720;
        const int cloc = rem >> 5;                   // 0..959 border cells
        const int q16  = rem & 31;                   // 16B chunk of 256 ch
        const int img  = ip >> 1;
        __hip_bfloat16* base = (ip & 1) ? vp : kp;
        int prow, pcol;
        if (cloc < 512) {                            // full pad rows 0-2,59-63
            const int r8 = cloc >> 6;
            prow = (r8 < 3) ? r8 : r8 + 56;
            pcol = cloc & 63;
        } else {                                     // side pads of rows 3..58
            const int c2 = cloc - 512;
            prow = 3 + (c2 >> 3);
            const int cc = c2 & 7;
            pcol = (cc < 3) ? cc : cc + 56;
        }
        *(uint4*)(base + (((size_t)(img * 64 + prow)) * 64 + pcol) * 256 + q16 * 8) =
            make_uint4(0u, 0u, 0u, 0u);
    }
}

// ================= 128x128 bf16 MFMA GEMM cores =================
// 256 thr = 4 waves; wave w owns quadrant (w>>1, w&1) as 4x4 16x16x32 frags.
// Staging in fragment order via global_load_lds: wave w DMAs A row-blocks
// 2w,2w+1 and B row-blocks 2w,2w+1 (block = 16 rows x 32 k = 64 lanes x 16 B).
#define GEMM128_BODY(EPILOGUE)                                                  \
    constexpr int K = 256;                                                      \
    __shared__ frag_ab As[8][64];   /* 8 KB */                                  \
    __shared__ frag_ab Bs[8][64];   /* 8 KB */                                  \
    const int tid  = threadIdx.x;                                               \
    const int lane = tid & 63;                                                  \
    const int w    = tid >> 6;                                                  \
    const int wm   = w >> 1, wn = w & 1;                                        \
    const int m0 = blockIdx.y * 128;                                            \
    const int n0 = blockIdx.x * 128;                                            \
    const int lrow = lane & 15;                                                 \
    const int lk   = (lane >> 4) * 8;                                           \
    const __hip_bfloat16* gA0 = A  + (size_t)(m0 + (2*w+0)*16 + lrow) * K + lk; \
    const __hip_bfloat16* gA1 = A  + (size_t)(m0 + (2*w+1)*16 + lrow) * K + lk; \
    const __hip_bfloat16* gB0 = BT + (size_t)(n0 + (2*w+0)*16 + lrow) * K + lk; \
    const __hip_bfloat16* gB1 = BT + (size_t)(n0 + (2*w+1)*16 + lrow) * K + lk; \
    f32x4 acc[4][4] = {};                                                       \
    for (int k0 = 0; k0 < K; k0 += 32) {                                        \
        gl_lds16(gA0 + k0, &As[2*w+0][0]);                                      \
        gl_lds16(gA1 + k0, &As[2*w+1][0]);                                      \
        gl_lds16(gB0 + k0, &Bs[2*w+0][0]);                                      \
        gl_lds16(gB1 + k0, &Bs[2*w+1][0]);                                      \
        __syncthreads();                                                        \
        frag_ab af[4], bf[4];                                                   \
        _Pragma("unroll")                                                       \
        for (int i = 0; i < 4; ++i) { af[i] = As[wm*4+i][lane]; bf[i] = Bs[wn*4+i][lane]; } \
        _Pragma("unroll")                                                       \
        for (int i = 0; i < 4; ++i)                                             \
            _Pragma("unroll")                                                   \
            for (int j = 0; j < 4; ++j)                                         \
                acc[i][j] = __builtin_amdgcn_mfma_f32_16x16x32_bf16(af[i], bf[j], acc[i][j], 0, 0, 0); \
        __syncthreads();                                                        \
    }                                                                           \
    const int rbase = (lane >> 4) * 4;                                          \
    const int cbase = lane & 15;                                                \
    _Pragma("unroll")                                                           \
    for (int fi = 0; fi < 4; ++fi) {                                            \
        const int rm = m0 + wm * 64 + fi * 16 + rbase;                          \
        _Pragma("unroll")                                                       \
        for (int fj = 0; fj < 4; ++fj) {                                        \
            const int cn = n0 + wn * 64 + fj * 16 + cbase;                      \
            const float bv = bias[cn];                                          \
            _Pragma("unroll")                                                   \
            for (int r = 0; r < 4; ++r) {                                       \
                const int m = rm + r;                                           \
                const float val = acc[fi][fj][r] + bv;                          \
                EPILOGUE                                                        \
            }                                                                   \
        }                                                                       \
    }

// QKV GEMM: N=768; cols 0-255 -> qf fp32 (scaled); 256-511 -> kp; 512-767 -> vp
__global__ __launch_bounds__(256) void gemm_qkv(
    const __hip_bfloat16* __restrict__ A,
    const __hip_bfloat16* __restrict__ BT,
    const float* __restrict__ bias,
    float* __restrict__ qf,
    __hip_bfloat16* __restrict__ kp,
    __hip_bfloat16* __restrict__ vp,
    float qscale)
{
    GEMM128_BODY({
        const int sel = cn >> 8;                       // 0=q,1=k,2=v (uniform/block)
        if (sel == 0) {
            qf[(size_t)m * 256 + cn] = val * qscale;
        } else {
            const int c  = cn & 255;
            const int b  = m / 3136;
            const int r2 = m % 3136;
            const int yy = r2 / 56;
            const int xx = r2 % 56;
            __hip_bfloat16* dst = (sel == 1) ? kp : vp;
            dst[(((size_t)(b * 64 + yy + 3)) * 64 + (xx + 3)) * 256 + c] =
                __float2bfloat16(val);
        }
    })
}

// proj GEMM: C fp32 [M][256] = A bf16 @ BT bf16 + bias
__global__ __launch_bounds__(256) void gemm_proj(
    const __hip_bfloat16* __restrict__ A,
    const __hip_bfloat16* __restrict__ BT,
    const float* __restrict__ bias,
    float* __restrict__ C)
{
    GEMM128_BODY({
        C[(size_t)m * 256 + cn] = val;
    })
}

// ================= neighborhood attention =================
// Block = 128 thr = 2 independent waves; wave = 4 tokens x 8 heads x 2 half-heads.
// Grid = 1568. Per ky the wave stages 10 cols x 256 ch bf16 (5 KB) of the padded
// k (then v) plane: 5x global_load_dwordx4 -> 5x ds_write_b128 into a padded
// LDS layout (col stride 264 halfwords = 528 B -> measured 0 bank conflicts),
// register-double-buffered: loads for ky+1 in flight while computing ky.
// Zero-padded planes => branch-free; OOB logit = rpb (reference semantics).
// __launch_bounds__(128, 2): VGPR cap 256. DO NOT raise the min-waves arg to 3:
// the ~170-VGPR cap spills logit[49] to scratch -> 1.4 GB of HBM spill traffic
// (measured round 6: FETCH 720 MB / WRITE 657 MB, 480 us).
__global__ __launch_bounds__(128, 2) void na2d_attn5(
    const float* __restrict__ qf,
    const __hip_bfloat16* __restrict__ kp,
    const __hip_bfloat16* __restrict__ vp,
    const float* __restrict__ rpb,
    __hip_bfloat16* __restrict__ out)
{
    const int tid  = threadIdx.x;
    const int wave = tid >> 6;
    const int lane = tid & 63;
    const int half = lane & 1;          // 16-ch half of a head
    const int h    = (lane >> 1) & 7;   // head
    const int tl   = (lane >> 4) & 3;   // token within wave's 4-token segment

    const int seg = blockIdx.x;         // 0..1567
    const int row = seg / 7;            // b*56 + y
    const int x0  = (seg % 7) * 8 + wave * 4;   // 0..52
    const int b   = row / 56;
    const int y   = row % 56;
    const int t   = row * 56 + x0 + tl;
    const int prow0 = b * 64 + y;       // padded plane row for ky=0

    __shared__ __hip_bfloat16 kbuf[2][2][10 * 264];   // [wave][parity] 20.6 KB
    __shared__ float srpb[8 * 49];

    for (int i = tid; i < 8 * 49; i += 128) srpb[i] = rpb[i];
    __syncthreads();                    // only barrier in the kernel

    // q: 16 fp32 channels (lanes of one token cover its 256 ch contiguously)
    float q[16];
    {
        const float4* qp = (const float4*)(qf + (size_t)t * 256 + h * 32 + half * 16);
        #pragma unroll
        for (int i = 0; i < 4; ++i) {
            const float4 v4 = qp[i];
            q[4 * i + 0] = v4.x; q[4 * i + 1] = v4.y;
            q[4 * i + 2] = v4.z; q[4 * i + 3] = v4.w;
        }
    }

    uint4 g[5];
    auto gload = [&](const __hip_bfloat16* plane, int ky) {
        const __hip_bfloat16* rb =
            plane + ((size_t)(prow0 + ky) * 64 + x0) * 256 + lane * 8;
        #pragma unroll
        for (int i = 0; i < 5; ++i) g[i] = *(const uint4*)(rb + i * 512);
    };
    auto lwrite = [&](int par) {
        char* base = (char*)&kbuf[wave][par][0];
        #pragma unroll
        for (int i = 0; i < 5; ++i) {
            const int unit = lane + i * 64;     // 0..319
            const int col  = unit >> 5;         // 0..9
            const int j    = unit & 31;         // 16B chunk
            *(uint4*)(base + col * 528 + j * 16) = g[i];
        }
    };

    float logit[49];

    // ---- QK phase ----
    gload(kp, 0);
    #pragma unroll
    for (int ky = 0; ky < 7; ++ky) {
        lwrite(ky & 1);
        if (ky < 6) gload(kp, ky + 1);          // next row in flight
        const char* kb = (const char*)&kbuf[wave][ky & 1][0];
        #pragma unroll
        for (int kx = 0; kx < 7; ++kx) {
            const uint4* p = (const uint4*)(kb + (tl + kx) * 528 + h * 64 + half * 32);
            float s = 0.f;
            #pragma unroll
            for (int qd = 0; qd < 2; ++qd) {
                const uint4 wv = p[qd];
                const int o8 = qd * 8;
                s += q[o8 + 0] * bflo(wv.x) + q[o8 + 1] * bfhi(wv.x)
                   + q[o8 + 2] * bflo(wv.y) + q[o8 + 3] * bfhi(wv.y)
                   + q[o8 + 4] * bflo(wv.z) + q[o8 + 5] * bfhi(wv.z)
                   + q[o8 + 6] * bflo(wv.w) + q[o8 + 7] * bfhi(wv.w);
            }
            logit[ky * 7 + kx] = s;
        }
    }

    // merge half-head partials (lane pairs differ only in `half`)
    #pragma unroll
    for (int kk = 0; kk < 49; ++kk)
        logit[kk] += __shfl_xor(logit[kk], 1, 64);

    // ---- softmax over 49 (+rpb; zero-pads give logit = rpb) ----
    const float* rp = &srpb[h * 49];
    float mx = -1e30f;
    #pragma unroll
    for (int kk = 0; kk < 49; ++kk) {
        logit[kk] += rp[kk];
        mx = fmaxf(mx, logit[kk]);
    }
    float ssum = 0.f;
    #pragma unroll
    for (int kk = 0; kk < 49; ++kk) {
        const float e = __expf(logit[kk] - mx);
        logit[kk] = e;
        ssum += e;
    }
    const float inv = 1.f / ssum;

    // ---- PV phase ----
    float o[16] = {};
    gload(vp, 0);
    #pragma unroll
    for (int ky = 0; ky < 7; ++ky) {
        lwrite(ky & 1);
        if (ky < 6) gload(vp, ky + 1);
        const char* vb = (const char*)&kbuf[wave][ky & 1][0];
        #pragma unroll
        for (int kx = 0; kx < 7; ++kx) {
            const float pr = logit[ky * 7 + kx];
            const uint4* p = (const uint4*)(vb + (tl + kx) * 528 + h * 64 + half * 32);
            #pragma unroll
            for (int qd = 0; qd < 2; ++qd) {
                const uint4 wv = p[qd];
                const int o8 = qd * 8;
                o[o8 + 0] += pr * bflo(wv.x); o[o8 + 1] += pr * bfhi(wv.x);
                o[o8 + 2] += pr * bflo(wv.y); o[o8 + 3] += pr * bfhi(wv.y);
                o[o8 + 4] += pr * bflo(wv.z); o[o8 + 5] += pr * bfhi(wv.z);
                o[o8 + 6] += pr * bflo(wv.w); o[o8 + 7] += pr * bfhi(wv.w);
            }
        }
    }

    // ---- store bf16 (feeds proj GEMM) ----
    union { uint4 u[2]; __hip_bfloat16 hh[16]; } ob;
    #pragma unroll
    for (int i = 0; i < 16; ++i) ob.hh[i] = __float2bfloat16(o[i] * inv);
    uint4* op = (uint4*)(out + (size_t)t * 256 + h * 32 + half * 16);
    op[0] = ob.u[0];
    op[1] = ob.u[1];
}

extern "C" void kernel_launch(void* const* d_in, const int* in_sizes, int n_in,
                              void* d_out, int out_size, void* d_ws, size_t ws_size,
                              hipStream_t stream)
{
    const float* x      = (const float*)d_in[0];   // (4,56,56,256)
    const float* w_qkv  = (const float*)d_in[1];   // (256,768)
    const float* b_qkv  = (const float*)d_in[2];   // (768,)
    const float* rpb    = (const float*)d_in[3];   // (8,49)
    const float* w_proj = (const float*)d_in[4];   // (256,256)
    const float* b_proj = (const float*)d_in[5];   // (256,)
    float* out = (float*)d_out;                    // (4,56,56,256) fp32

    const int M = 12544;

    char* wsp = (char*)d_ws;
    float* qf = (float*)wsp;                      wsp += (size_t)M * 256 * 4;   // 12.85 MB
    __hip_bfloat16* kp    = (__hip_bfloat16*)wsp; wsp += (size_t)4 * 64 * 64 * 256 * 2; // 8.39 MB
    __hip_bfloat16* vp    = (__hip_bfloat16*)wsp; wsp += (size_t)4 * 64 * 64 * 256 * 2; // 8.39 MB
    __hip_bfloat16* xb    = (__hip_bfloat16*)wsp; wsp += (size_t)M * 256 * 2;
    __hip_bfloat16* attnb = (__hip_bfloat16*)wsp; wsp += (size_t)M * 256 * 2;
    __hip_bfloat16* wqkvT = (__hip_bfloat16*)wsp; wsp += (size_t)768 * 256 * 2;
    __hip_bfloat16* wprojT= (__hip_bfloat16*)wsp; wsp += (size_t)256 * 256 * 2;

    const float scale = 0.17677669529663689f;  // 32^-0.5

    // fused prep: x->bf16, both weight transposes, pad-border zero of kp/vp
    prep<<<5120, 256, 0, stream>>>(x, xb, w_qkv, wqkvT, w_proj, wprojT, kp, vp);

    // qkv = xb @ wqkvT^T + b_qkv; q fp32 scaled -> qf; k/v bf16 -> padded planes
    gemm_qkv<<<dim3(6, 98), 256, 0, stream>>>(xb, wqkvT, b_qkv, qf, kp, vp, scale);

    // attention: 1568 blocks x 128 threads (2 independent waves x 4 tokens)
    na2d_attn5<<<1568, 128, 0, stream>>>(qf, kp, vp, rpb, attnb);

    // out = attnb @ wprojT^T + b_proj
    gemm_proj<<<dim3(2, 98), 256, 0, stream>>>(attnb, wprojT, b_proj, out);
}

// Round 8
// 269.038 us; speedup vs baseline: 2.1558x; 1.3566x over previous
//
#include <hip/hip_runtime.h>
#include <hip/hip_bf16.h>

// Shapes (fixed): B=4, H=56, W=56, C=256, NH=8, HD=32, KS=7, PAD=3
// tokens M = 4*56*56 = 12544. Padded k/v planes: [4][64][64][256] bf16,
// interior token (y,x) at plane row y+3, col x+3; border zeroed by prep.

using frag_ab = __attribute__((ext_vector_type(8))) short;  // 8 bf16 (4 VGPRs)
using f32x4   = __attribute__((ext_vector_type(4))) float;  // 4 fp32 acc

typedef const __attribute__((address_space(1))) unsigned int* gas_u32;
typedef __attribute__((address_space(3))) unsigned int*       las_u32;

__device__ __forceinline__ void gl_lds16(const void* g, void* l) {
    // async global->LDS DMA, 16 B/lane; LDS dst = wave-uniform base + lane*16
    __builtin_amdgcn_global_load_lds((gas_u32)g, (las_u32)l, 16, 0, 0);
}

__device__ __forceinline__ float bflo(unsigned int u) { return __uint_as_float(u << 16); }
__device__ __forceinline__ float bfhi(unsigned int u) { return __uint_as_float(u & 0xffff0000u); }

// ================= fused prep =================
// blocks [0,3136):    x fp32 -> xb bf16 (float4/thread)
// blocks [3136,3904): w_qkv [256][768] -> wqkvT [768][256] bf16
// blocks [3904,4160): w_proj [256][256] -> wprojT [256][256] bf16
// blocks [4160,5120): zero the 960 border cols of each padded plane
__global__ __launch_bounds__(256) void prep(
    const float* __restrict__ x,      __hip_bfloat16* __restrict__ xb,
    const float* __restrict__ w_qkv,  __hip_bfloat16* __restrict__ wqkvT,
    const float* __restrict__ w_proj, __hip_bfloat16* __restrict__ wprojT,
    __hip_bfloat16* __restrict__ kp,  __hip_bfloat16* __restrict__ vp)
{
    const int bid = blockIdx.x;
    const int tid = threadIdx.x;
    if (bid < 3136) {
        const int i = bid * 256 + tid;            // over M*256/4 = 802816
        const float4 v = ((const float4*)x)[i];
        union { ushort4 u; __hip_bfloat16 h[4]; } o;
        o.h[0] = __float2bfloat16(v.x); o.h[1] = __float2bfloat16(v.y);
        o.h[2] = __float2bfloat16(v.z); o.h[3] = __float2bfloat16(v.w);
        ((ushort4*)xb)[i] = o.u;
    } else if (bid < 3904) {
        const int idx = (bid - 3136) * 256 + tid; // over 768*256
        const int k = idx & 255, n = idx >> 8;
        wqkvT[idx] = __float2bfloat16(w_qkv[k * 768 + n]);
    } else if (bid < 4160) {
        const int idx = (bid - 3904) * 256 + tid; // over 256*256
        const int k = idx & 255, n = idx >> 8;
        wprojT[idx] = __float2bfloat16(w_proj[k * 256 + n]);
    } else {
        const int u    = (bid - 4160) * 256 + tid;   // over 8*30720
        const int ip   = u / 30720;                  // img*2 + plane
        const int rem  = u - ip * 30720;
        const int cloc = rem >> 5;                   // 0..959 border cells
        const int q16  = rem & 31;                   // 16B chunk of 256 ch
        const int img  = ip >> 1;
        __hip_bfloat16* base = (ip & 1) ? vp : kp;
        int prow, pcol;
        if (cloc < 512) {                            // full pad rows 0-2,59-63
            const int r8 = cloc >> 6;
            prow = (r8 < 3) ? r8 : r8 + 56;
            pcol = cloc & 63;
        } else {                                     // side pads of rows 3..58
            const int c2 = cloc - 512;
            prow = 3 + (c2 >> 3);
            const int cc = c2 & 7;
            pcol = (cc < 3) ? cc : cc + 56;
        }
        *(uint4*)(base + (((size_t)(img * 64 + prow)) * 64 + pcol) * 256 + q16 * 8) =
            make_uint4(0u, 0u, 0u, 0u);
    }
}

// ================= 128x128 bf16 MFMA GEMM cores =================
// 256 thr = 4 waves; wave w owns quadrant (w>>1, w&1) as 4x4 16x16x32 frags.
// Staging in fragment order via global_load_lds: wave w DMAs A row-blocks
// 2w,2w+1 and B row-blocks 2w,2w+1 (block = 16 rows x 32 k = 64 lanes x 16 B).
#define GEMM128_BODY(EPILOGUE)                                                  \
    constexpr int K = 256;                                                      \
    __shared__ frag_ab As[8][64];   /* 8 KB */                                  \
    __shared__ frag_ab Bs[8][64];   /* 8 KB */                                  \
    const int tid  = threadIdx.x;                                               \
    const int lane = tid & 63;                                                  \
    const int w    = tid >> 6;                                                  \
    const int wm   = w >> 1, wn = w & 1;                                        \
    const int m0 = blockIdx.y * 128;                                            \
    const int n0 = blockIdx.x * 128;                                            \
    const int lrow = lane & 15;                                                 \
    const int lk   = (lane >> 4) * 8;                                           \
    const __hip_bfloat16* gA0 = A  + (size_t)(m0 + (2*w+0)*16 + lrow) * K + lk; \
    const __hip_bfloat16* gA1 = A  + (size_t)(m0 + (2*w+1)*16 + lrow) * K + lk; \
    const __hip_bfloat16* gB0 = BT + (size_t)(n0 + (2*w+0)*16 + lrow) * K + lk; \
    const __hip_bfloat16* gB1 = BT + (size_t)(n0 + (2*w+1)*16 + lrow) * K + lk; \
    f32x4 acc[4][4] = {};                                                       \
    for (int k0 = 0; k0 < K; k0 += 32) {                                        \
        gl_lds16(gA0 + k0, &As[2*w+0][0]);                                      \
        gl_lds16(gA1 + k0, &As[2*w+1][0]);                                      \
        gl_lds16(gB0 + k0, &Bs[2*w+0][0]);                                      \
        gl_lds16(gB1 + k0, &Bs[2*w+1][0]);                                      \
        __syncthreads();                                                        \
        frag_ab af[4], bf[4];                                                   \
        _Pragma("unroll")                                                       \
        for (int i = 0; i < 4; ++i) { af[i] = As[wm*4+i][lane]; bf[i] = Bs[wn*4+i][lane]; } \
        _Pragma("unroll")                                                       \
        for (int i = 0; i < 4; ++i)                                             \
            _Pragma("unroll")                                                   \
            for (int j = 0; j < 4; ++j)                                         \
                acc[i][j] = __builtin_amdgcn_mfma_f32_16x16x32_bf16(af[i], bf[j], acc[i][j], 0, 0, 0); \
        __syncthreads();                                                        \
    }                                                                           \
    const int rbase = (lane >> 4) * 4;                                          \
    const int cbase = lane & 15;                                                \
    _Pragma("unroll")                                                           \
    for (int fi = 0; fi < 4; ++fi) {                                            \
        const int rm = m0 + wm * 64 + fi * 16 + rbase;                          \
        _Pragma("unroll")                                                       \
        for (int fj = 0; fj < 4; ++fj) {                                        \
            const int cn = n0 + wn * 64 + fj * 16 + cbase;                      \
            const float bv = bias[cn];                                          \
            _Pragma("unroll")                                                   \
            for (int r = 0; r < 4; ++r) {                                       \
                const int m = rm + r;                                           \
                const float val = acc[fi][fj][r] + bv;                          \
                EPILOGUE                                                        \
            }                                                                   \
        }                                                                       \
    }

// QKV GEMM: N=768; cols 0-255 -> qf fp32 (scaled); 256-511 -> kp; 512-767 -> vp
__global__ __launch_bounds__(256) void gemm_qkv(
    const __hip_bfloat16* __restrict__ A,
    const __hip_bfloat16* __restrict__ BT,
    const float* __restrict__ bias,
    float* __restrict__ qf,
    __hip_bfloat16* __restrict__ kp,
    __hip_bfloat16* __restrict__ vp,
    float qscale)
{
    GEMM128_BODY({
        const int sel = cn >> 8;                       // 0=q,1=k,2=v (uniform/block)
        if (sel == 0) {
            qf[(size_t)m * 256 + cn] = val * qscale;
        } else {
            const int c  = cn & 255;
            const int b  = m / 3136;
            const int r2 = m % 3136;
            const int yy = r2 / 56;
            const int xx = r2 % 56;
            __hip_bfloat16* dst = (sel == 1) ? kp : vp;
            dst[(((size_t)(b * 64 + yy + 3)) * 64 + (xx + 3)) * 256 + c] =
                __float2bfloat16(val);
        }
    })
}

// proj GEMM: C fp32 [M][256] = A bf16 @ BT bf16 + bias
__global__ __launch_bounds__(256) void gemm_proj(
    const __hip_bfloat16* __restrict__ A,
    const __hip_bfloat16* __restrict__ BT,
    const float* __restrict__ bias,
    float* __restrict__ C)
{
    GEMM128_BODY({
        C[(size_t)m * 256 + cn] = val;
    })
}

// ================= neighborhood attention =================
// ONE WAVE per block (64 thr) = 4 tokens x 8 heads x 2 half-heads; grid 3136.
// Plain __launch_bounds__(64): NEVER set the min-waves arg here — measured
// R6 (arg=3): VGPR capped 84 -> logit[49] spilled -> 1.4 GB HBM scratch, 480us;
// R7 (arg=2): cap 128 -> still spilled 0.8 GB, 270us. Uncapped (R4/R5) = no spill.
// Per ky: stage 10 cols x 256 ch bf16 (5 KB) of the padded k (then v) plane:
// 5x global_load_dwordx4 (row ky+1 issued before computing row ky -> latency
// hidden) -> 5x ds_write_b128 into LDS with 528 B col stride (132 words == 4
// mod 32 -> measured 0 bank conflicts R6/R7). Single buffer: same-wave DS ops
// execute in order, so write(ky+1) cannot pass the reads of compute(ky).
// Zero-padded planes => branch-free; OOB logit = rpb (reference semantics).
__global__ __launch_bounds__(64) void na2d_attn6(
    const float* __restrict__ qf,
    const __hip_bfloat16* __restrict__ kp,
    const __hip_bfloat16* __restrict__ vp,
    const float* __restrict__ rpb,
    __hip_bfloat16* __restrict__ out)
{
    const int lane = threadIdx.x;       // 0..63
    const int half = lane & 1;          // 16-ch half of a head
    const int h    = (lane >> 1) & 7;   // head
    const int tl   = (lane >> 4) & 3;   // token within 4-token segment

    const int seg = blockIdx.x;         // 0..3135
    const int row = seg / 14;           // b*56 + y
    const int x0  = (seg % 14) * 4;     // 0..52
    const int b   = row / 56;
    const int y   = row % 56;
    const int t   = row * 56 + x0 + tl;
    const int prow0 = b * 64 + y;       // padded plane row for ky=0

    __shared__ __hip_bfloat16 kbuf[10 * 264];   // 5.28 KB, col stride 528 B
    __shared__ float srpb[8 * 49];

    for (int i = lane; i < 8 * 49; i += 64) srpb[i] = rpb[i];
    __syncthreads();                    // single-wave barrier: cheap

    // q: 16 fp32 channels (4 tokens' 256 ch are contiguous across the wave)
    float q[16];
    {
        const float4* qp = (const float4*)(qf + (size_t)t * 256 + h * 32 + half * 16);
        #pragma unroll
        for (int i = 0; i < 4; ++i) {
            const float4 v4 = qp[i];
            q[4 * i + 0] = v4.x; q[4 * i + 1] = v4.y;
            q[4 * i + 2] = v4.z; q[4 * i + 3] = v4.w;
        }
    }

    uint4 g[5];
    auto gload = [&](const __hip_bfloat16* plane, int ky) {
        const __hip_bfloat16* rb =
            plane + ((size_t)(prow0 + ky) * 64 + x0) * 256 + lane * 8;
        #pragma unroll
        for (int i = 0; i < 5; ++i) g[i] = *(const uint4*)(rb + i * 512);
    };
    auto lwrite = [&]() {
        char* base = (char*)&kbuf[0];
        #pragma unroll
        for (int i = 0; i < 5; ++i) {
            const int unit = lane + i * 64;     // 0..319
            const int col  = unit >> 5;         // 0..9
            const int j    = unit & 31;         // 16B chunk
            *(uint4*)(base + col * 528 + j * 16) = g[i];
        }
    };

    float logit[49];

    // ---- QK phase ----
    gload(kp, 0);
    #pragma unroll
    for (int ky = 0; ky < 7; ++ky) {
        lwrite();                               // waits vmcnt for row ky's g
        if (ky < 6) gload(kp, ky + 1);          // next row in flight
        const char* kb = (const char*)&kbuf[0];
        #pragma unroll
        for (int kx = 0; kx < 7; ++kx) {
            const uint4* p = (const uint4*)(kb + (tl + kx) * 528 + h * 64 + half * 32);
            float s = 0.f;
            #pragma unroll
            for (int qd = 0; qd < 2; ++qd) {
                const uint4 wv = p[qd];
                const int o8 = qd * 8;
                s += q[o8 + 0] * bflo(wv.x) + q[o8 + 1] * bfhi(wv.x)
                   + q[o8 + 2] * bflo(wv.y) + q[o8 + 3] * bfhi(wv.y)
                   + q[o8 + 4] * bflo(wv.z) + q[o8 + 5] * bfhi(wv.z)
                   + q[o8 + 6] * bflo(wv.w) + q[o8 + 7] * bfhi(wv.w);
            }
            logit[ky * 7 + kx] = s;
        }
    }

    // merge half-head partials (lane pairs differ only in `half`)
    #pragma unroll
    for (int kk = 0; kk < 49; ++kk)
        logit[kk] += __shfl_xor(logit[kk], 1, 64);

    // ---- softmax over 49 (+rpb; zero-pads give logit = rpb) ----
    const float* rp = &srpb[h * 49];
    float mx = -1e30f;
    #pragma unroll
    for (int kk = 0; kk < 49; ++kk) {
        logit[kk] += rp[kk];
        mx = fmaxf(mx, logit[kk]);
    }
    float ssum = 0.f;
    #pragma unroll
    for (int kk = 0; kk < 49; ++kk) {
        const float e = __expf(logit[kk] - mx);
        logit[kk] = e;
        ssum += e;
    }
    const float inv = 1.f / ssum;

    // ---- PV phase ----
    float o[16] = {};
    gload(vp, 0);
    #pragma unroll
    for (int ky = 0; ky < 7; ++ky) {
        lwrite();
        if (ky < 6) gload(vp, ky + 1);
        const char* vb = (const char*)&kbuf[0];
        #pragma unroll
        for (int kx = 0; kx < 7; ++kx) {
            const float pr = logit[ky * 7 + kx];
            const uint4* p = (const uint4*)(vb + (tl + kx) * 528 + h * 64 + half * 32);
            #pragma unroll
            for (int qd = 0; qd < 2; ++qd) {
                const uint4 wv = p[qd];
                const int o8 = qd * 8;
                o[o8 + 0] += pr * bflo(wv.x); o[o8 + 1] += pr * bfhi(wv.x);
                o[o8 + 2] += pr * bflo(wv.y); o[o8 + 3] += pr * bfhi(wv.y);
                o[o8 + 4] += pr * bflo(wv.z); o[o8 + 5] += pr * bfhi(wv.z);
                o[o8 + 6] += pr * bflo(wv.w); o[o8 + 7] += pr * bfhi(wv.w);
            }
        }
    }

    // ---- store bf16 (feeds proj GEMM) ----
    union { uint4 u[2]; __hip_bfloat16 hh[16]; } ob;
    #pragma unroll
    for (int i = 0; i < 16; ++i) ob.hh[i] = __float2bfloat16(o[i] * inv);
    uint4* op = (uint4*)(out + (size_t)t * 256 + h * 32 + half * 16);
    op[0] = ob.u[0];
    op[1] = ob.u[1];
}

extern "C" void kernel_launch(void* const* d_in, const int* in_sizes, int n_in,
                              void* d_out, int out_size, void* d_ws, size_t ws_size,
                              hipStream_t stream)
{
    const float* x      = (const float*)d_in[0];   // (4,56,56,256)
    const float* w_qkv  = (const float*)d_in[1];   // (256,768)
    const float* b_qkv  = (const float*)d_in[2];   // (768,)
    const float* rpb    = (const float*)d_in[3];   // (8,49)
    const float* w_proj = (const float*)d_in[4];   // (256,256)
    const float* b_proj = (const float*)d_in[5];   // (256,)
    float* out = (float*)d_out;                    // (4,56,56,256) fp32

    const int M = 12544;

    char* wsp = (char*)d_ws;
    float* qf = (float*)wsp;                      wsp += (size_t)M * 256 * 4;   // 12.85 MB
    __hip_bfloat16* kp    = (__hip_bfloat16*)wsp; wsp += (size_t)4 * 64 * 64 * 256 * 2; // 8.39 MB
    __hip_bfloat16* vp    = (__hip_bfloat16*)wsp; wsp += (size_t)4 * 64 * 64 * 256 * 2; // 8.39 MB
    __hip_bfloat16* xb    = (__hip_bfloat16*)wsp; wsp += (size_t)M * 256 * 2;
    __hip_bfloat16* attnb = (__hip_bfloat16*)wsp; wsp += (size_t)M * 256 * 2;
    __hip_bfloat16* wqkvT = (__hip_bfloat16*)wsp; wsp += (size_t)768 * 256 * 2;
    __hip_bfloat16* wprojT= (__hip_bfloat16*)wsp; wsp += (size_t)256 * 256 * 2;

    const float scale = 0.17677669529663689f;  // 32^-0.5

    // fused prep: x->bf16, both weight transposes, pad-border zero of kp/vp
    prep<<<5120, 256, 0, stream>>>(x, xb, w_qkv, wqkvT, w_proj, wprojT, kp, vp);

    // qkv = xb @ wqkvT^T + b_qkv; q fp32 scaled -> qf; k/v bf16 -> padded planes
    gemm_qkv<<<dim3(6, 98), 256, 0, stream>>>(xb, wqkvT, b_qkv, qf, kp, vp, scale);

    // attention: 3136 blocks x 64 threads (one wave: 4 tokens x 8 heads x 2 halves)
    na2d_attn6<<<3136, 64, 0, stream>>>(qf, kp, vp, rpb, attnb);

    // out = attnb @ wprojT^T + b_proj
    gemm_proj<<<dim3(2, 98), 256, 0, stream>>>(attnb, wprojT, b_proj, out);
}

// Round 9
// 233.920 us; speedup vs baseline: 2.4794x; 1.1501x over previous
//
#include <hip/hip_runtime.h>
#include <hip/hip_bf16.h>

// Shapes (fixed): B=4, H=56, W=56, C=256, NH=8, HD=32, KS=7, PAD=3
// tokens M = 4*56*56 = 12544. Padded k/v planes: [4][64][64][256] bf16,
// interior token (y,x) at plane row y+3, col x+3; border zeroed by prep.

using frag_ab = __attribute__((ext_vector_type(8))) short;  // 8 bf16 (4 VGPRs)
using f32x4   = __attribute__((ext_vector_type(4))) float;  // 4 fp32 acc

typedef const __attribute__((address_space(1))) unsigned int* gas_u32;
typedef __attribute__((address_space(3))) unsigned int*       las_u32;

__device__ __forceinline__ void gl_lds16(const void* g, void* l) {
    // async global->LDS DMA, 16 B/lane; LDS dst = wave-uniform base + lane*16
    __builtin_amdgcn_global_load_lds((gas_u32)g, (las_u32)l, 16, 0, 0);
}

__device__ __forceinline__ float bflo(unsigned int u) { return __uint_as_float(u << 16); }
__device__ __forceinline__ float bfhi(unsigned int u) { return __uint_as_float(u & 0xffff0000u); }

// ================= fused prep =================
// blocks [0,3136):    x fp32 -> xb bf16 (float4/thread)
// blocks [3136,3904): w_qkv [256][768] -> wqkvT [768][256] bf16
// blocks [3904,4160): w_proj [256][256] -> wprojT [256][256] bf16
// blocks [4160,5120): zero the 960 border cols of each padded plane
__global__ __launch_bounds__(256) void prep(
    const float* __restrict__ x,      __hip_bfloat16* __restrict__ xb,
    const float* __restrict__ w_qkv,  __hip_bfloat16* __restrict__ wqkvT,
    const float* __restrict__ w_proj, __hip_bfloat16* __restrict__ wprojT,
    __hip_bfloat16* __restrict__ kp,  __hip_bfloat16* __restrict__ vp)
{
    const int bid = blockIdx.x;
    const int tid = threadIdx.x;
    if (bid < 3136) {
        const int i = bid * 256 + tid;            // over M*256/4 = 802816
        const float4 v = ((const float4*)x)[i];
        union { ushort4 u; __hip_bfloat16 h[4]; } o;
        o.h[0] = __float2bfloat16(v.x); o.h[1] = __float2bfloat16(v.y);
        o.h[2] = __float2bfloat16(v.z); o.h[3] = __float2bfloat16(v.w);
        ((ushort4*)xb)[i] = o.u;
    } else if (bid < 3904) {
        const int idx = (bid - 3136) * 256 + tid; // over 768*256
        const int k = idx & 255, n = idx >> 8;
        wqkvT[idx] = __float2bfloat16(w_qkv[k * 768 + n]);
    } else if (bid < 4160) {
        const int idx = (bid - 3904) * 256 + tid; // over 256*256
        const int k = idx & 255, n = idx >> 8;
        wprojT[idx] = __float2bfloat16(w_proj[k * 256 + n]);
    } else {
        const int u    = (bid - 4160) * 256 + tid;   // over 8*30720
        const int ip   = u / 30720;                  // img*2 + plane
        const int rem  = u - ip * 30720;
        const int cloc = rem >> 5;                   // 0..959 border cells
        const int q16  = rem & 31;                   // 16B chunk of 256 ch
        const int img  = ip >> 1;
        __hip_bfloat16* base = (ip & 1) ? vp : kp;
        int prow, pcol;
        if (cloc < 512) {                            // full pad rows 0-2,59-63
            const int r8 = cloc >> 6;
            prow = (r8 < 3) ? r8 : r8 + 56;
            pcol = cloc & 63;
        } else {                                     // side pads of rows 3..58
            const int c2 = cloc - 512;
            prow = 3 + (c2 >> 3);
            const int cc = c2 & 7;
            pcol = (cc < 3) ? cc : cc + 56;
        }
        *(uint4*)(base + (((size_t)(img * 64 + prow)) * 64 + pcol) * 256 + q16 * 8) =
            make_uint4(0u, 0u, 0u, 0u);
    }
}

// ================= 128x128 bf16 MFMA GEMM cores =================
// 256 thr = 4 waves; wave w owns quadrant (w>>1, w&1) as 4x4 16x16x32 frags.
// Staging in fragment order via global_load_lds: wave w DMAs A row-blocks
// 2w,2w+1 and B row-blocks 2w,2w+1 (block = 16 rows x 32 k = 64 lanes x 16 B).
#define GEMM128_BODY(EPILOGUE)                                                  \
    constexpr int K = 256;                                                      \
    __shared__ frag_ab As[8][64];   /* 8 KB */                                  \
    __shared__ frag_ab Bs[8][64];   /* 8 KB */                                  \
    const int tid  = threadIdx.x;                                               \
    const int lane = tid & 63;                                                  \
    const int w    = tid >> 6;                                                  \
    const int wm   = w >> 1, wn = w & 1;                                        \
    const int m0 = blockIdx.y * 128;                                            \
    const int n0 = blockIdx.x * 128;                                            \
    const int lrow = lane & 15;                                                 \
    const int lk   = (lane >> 4) * 8;                                           \
    const __hip_bfloat16* gA0 = A  + (size_t)(m0 + (2*w+0)*16 + lrow) * K + lk; \
    const __hip_bfloat16* gA1 = A  + (size_t)(m0 + (2*w+1)*16 + lrow) * K + lk; \
    const __hip_bfloat16* gB0 = BT + (size_t)(n0 + (2*w+0)*16 + lrow) * K + lk; \
    const __hip_bfloat16* gB1 = BT + (size_t)(n0 + (2*w+1)*16 + lrow) * K + lk; \
    f32x4 acc[4][4] = {};                                                       \
    for (int k0 = 0; k0 < K; k0 += 32) {                                        \
        gl_lds16(gA0 + k0, &As[2*w+0][0]);                                      \
        gl_lds16(gA1 + k0, &As[2*w+1][0]);                                      \
        gl_lds16(gB0 + k0, &Bs[2*w+0][0]);                                      \
        gl_lds16(gB1 + k0, &Bs[2*w+1][0]);                                      \
        __syncthreads();                                                        \
        frag_ab af[4], bf[4];                                                   \
        _Pragma("unroll")                                                       \
        for (int i = 0; i < 4; ++i) { af[i] = As[wm*4+i][lane]; bf[i] = Bs[wn*4+i][lane]; } \
        _Pragma("unroll")                                                       \
        for (int i = 0; i < 4; ++i)                                             \
            _Pragma("unroll")                                                   \
            for (int j = 0; j < 4; ++j)                                         \
                acc[i][j] = __builtin_amdgcn_mfma_f32_16x16x32_bf16(af[i], bf[j], acc[i][j], 0, 0, 0); \
        __syncthreads();                                                        \
    }                                                                           \
    const int rbase = (lane >> 4) * 4;                                          \
    const int cbase = lane & 15;                                                \
    _Pragma("unroll")                                                           \
    for (int fi = 0; fi < 4; ++fi) {                                            \
        const int rm = m0 + wm * 64 + fi * 16 + rbase;                          \
        _Pragma("unroll")                                                       \
        for (int fj = 0; fj < 4; ++fj) {                                        \
            const int cn = n0 + wn * 64 + fj * 16 + cbase;                      \
            const float bv = bias[cn];                                          \
            _Pragma("unroll")                                                   \
            for (int r = 0; r < 4; ++r) {                                       \
                const int m = rm + r;                                           \
                const float val = acc[fi][fj][r] + bv;                          \
                EPILOGUE                                                        \
            }                                                                   \
        }                                                                       \
    }

// QKV GEMM: N=768; cols 0-255 -> qf fp32 (scaled); 256-511 -> kp; 512-767 -> vp
__global__ __launch_bounds__(256) void gemm_qkv(
    const __hip_bfloat16* __restrict__ A,
    const __hip_bfloat16* __restrict__ BT,
    const float* __restrict__ bias,
    float* __restrict__ qf,
    __hip_bfloat16* __restrict__ kp,
    __hip_bfloat16* __restrict__ vp,
    float qscale)
{
    GEMM128_BODY({
        const int sel = cn >> 8;                       // 0=q,1=k,2=v (uniform/block)
        if (sel == 0) {
            qf[(size_t)m * 256 + cn] = val * qscale;
        } else {
            const int c  = cn & 255;
            const int b  = m / 3136;
            const int r2 = m % 3136;
            const int yy = r2 / 56;
            const int xx = r2 % 56;
            __hip_bfloat16* dst = (sel == 1) ? kp : vp;
            dst[(((size_t)(b * 64 + yy + 3)) * 64 + (xx + 3)) * 256 + c] =
                __float2bfloat16(val);
        }
    })
}

// proj GEMM: C fp32 [M][256] = A bf16 @ BT bf16 + bias
__global__ __launch_bounds__(256) void gemm_proj(
    const __hip_bfloat16* __restrict__ A,
    const __hip_bfloat16* __restrict__ BT,
    const float* __restrict__ bias,
    float* __restrict__ C)
{
    GEMM128_BODY({
        C[(size_t)m * 256 + cn] = val;
    })
}

// ================= neighborhood attention, single-pass online softmax =======
// ONE WAVE per block (64 thr) = 4 tokens x 8 heads x 2 half-heads; grid 3136.
// Plain __launch_bounds__(64) and NO persistent logit[49]: rounds 6-8 showed
// the two-phase design's live set (logit[49] + staging) exceeds 256 VGPRs and
// spills to HBM scratch no matter the launch-bounds cap (R8: VGPR=256, 109 MB
// spill stores). Single-pass keeps only (m, l, o[16]) + transient lg[7].
// Per ky: stage k-row AND v-row (10 cols x 256 ch bf16 each) into separate
// LDS buffers (528 B col stride, measured 0 conflicts R6-R8); v-row loads are
// in flight during QK compute, next k-row during the online update.
// Zero-padded planes => branch-free; OOB rows/cols give logit = rpb only and
// v = 0 -- exactly the reference's zero-pad softmax semantics.
__global__ __launch_bounds__(64) void na2d_attn7(
    const float* __restrict__ qf,
    const __hip_bfloat16* __restrict__ kp,
    const __hip_bfloat16* __restrict__ vp,
    const float* __restrict__ rpb,
    __hip_bfloat16* __restrict__ out)
{
    const int lane = threadIdx.x;       // 0..63
    const int half = lane & 1;          // 16-ch half of a head
    const int h    = (lane >> 1) & 7;   // head
    const int tl   = (lane >> 4) & 3;   // token within 4-token segment

    const int seg = blockIdx.x;         // 0..3135
    const int row = seg / 14;           // b*56 + y
    const int x0  = (seg % 14) * 4;     // 0..52
    const int b   = row / 56;
    const int y   = row % 56;
    const int t   = row * 56 + x0 + tl;
    const int prow0 = b * 64 + y;       // padded plane row for ky=0

    __shared__ __hip_bfloat16 kbuf[10 * 264];   // 5.28 KB, col stride 528 B
    __shared__ __hip_bfloat16 vbuf[10 * 264];   // 5.28 KB
    __shared__ float srpb[8 * 49];

    for (int i = lane; i < 8 * 49; i += 64) srpb[i] = rpb[i];
    __syncthreads();                    // single-wave barrier: cheap

    // q: 16 fp32 channels (4 tokens' 256 ch are contiguous across the wave)
    float q[16];
    {
        const float4* qp = (const float4*)(qf + (size_t)t * 256 + h * 32 + half * 16);
        #pragma unroll
        for (int i = 0; i < 4; ++i) {
            const float4 v4 = qp[i];
            q[4 * i + 0] = v4.x; q[4 * i + 1] = v4.y;
            q[4 * i + 2] = v4.z; q[4 * i + 3] = v4.w;
        }
    }

    uint4 gk[5], gv[5];
    auto gload = [&](const __hip_bfloat16* plane, int ky, uint4* g) {
        const __hip_bfloat16* rb =
            plane + ((size_t)(prow0 + ky) * 64 + x0) * 256 + lane * 8;
        #pragma unroll
        for (int i = 0; i < 5; ++i) g[i] = *(const uint4*)(rb + i * 512);
    };
    auto lwrite = [&](__hip_bfloat16* buf, const uint4* g) {
        char* base = (char*)buf;
        #pragma unroll
        for (int i = 0; i < 5; ++i) {
            const int unit = lane + i * 64;     // 0..319
            const int col  = unit >> 5;         // 0..9 (token in window)
            const int j    = unit & 31;         // 16B chunk of 512 B token
            *(uint4*)(base + col * 528 + j * 16) = g[i];
        }
    };

    const float* rp = &srpb[h * 49];
    float m = -1e30f, l = 0.f;
    float o[16] = {};

    gload(kp, 0, gk);
    #pragma unroll
    for (int ky = 0; ky < 7; ++ky) {
        lwrite(kbuf, gk);                       // waits vmcnt for gk
        gload(vp, ky, gv);                      // v row in flight during QK
        // ---- 7 row logits from kbuf ----
        float lg[7];
        #pragma unroll
        for (int kx = 0; kx < 7; ++kx) {
            const uint4* p = (const uint4*)((const char*)kbuf +
                                            (tl + kx) * 528 + h * 64 + half * 32);
            float s = 0.f;
            #pragma unroll
            for (int qd = 0; qd < 2; ++qd) {
                const uint4 wv = p[qd];
                const int o8 = qd * 8;
                s += q[o8 + 0] * bflo(wv.x) + q[o8 + 1] * bfhi(wv.x)
                   + q[o8 + 2] * bflo(wv.y) + q[o8 + 3] * bfhi(wv.y)
                   + q[o8 + 4] * bflo(wv.z) + q[o8 + 5] * bfhi(wv.z)
                   + q[o8 + 6] * bflo(wv.w) + q[o8 + 7] * bfhi(wv.w);
            }
            lg[kx] = s;
        }
        lwrite(vbuf, gv);                       // waits vmcnt for gv
        if (ky < 6) gload(kp, ky + 1, gk);      // next k row in flight
        // ---- merge half-head partials + rpb ----
        #pragma unroll
        for (int kx = 0; kx < 7; ++kx) {
            lg[kx] += __shfl_xor(lg[kx], 1, 64);
            lg[kx] += rp[ky * 7 + kx];
        }
        // ---- online softmax update ----
        float rmax = lg[0];
        #pragma unroll
        for (int kx = 1; kx < 7; ++kx) rmax = fmaxf(rmax, lg[kx]);
        const float mnew  = fmaxf(m, rmax);
        const float alpha = __expf(m - mnew);   // ky=0: exp(-inf)=0
        m = mnew;
        l *= alpha;
        #pragma unroll
        for (int i = 0; i < 16; ++i) o[i] *= alpha;
        #pragma unroll
        for (int kx = 0; kx < 7; ++kx) {
            const float pr = __expf(lg[kx] - mnew);
            l += pr;
            const uint4* p = (const uint4*)((const char*)vbuf +
                                            (tl + kx) * 528 + h * 64 + half * 32);
            #pragma unroll
            for (int qd = 0; qd < 2; ++qd) {
                const uint4 wv = p[qd];
                const int o8 = qd * 8;
                o[o8 + 0] += pr * bflo(wv.x); o[o8 + 1] += pr * bfhi(wv.x);
                o[o8 + 2] += pr * bflo(wv.y); o[o8 + 3] += pr * bfhi(wv.y);
                o[o8 + 4] += pr * bflo(wv.z); o[o8 + 5] += pr * bfhi(wv.z);
                o[o8 + 6] += pr * bflo(wv.w); o[o8 + 7] += pr * bfhi(wv.w);
            }
        }
    }

    // ---- store bf16 (feeds proj GEMM) ----
    const float inv = 1.f / l;
    union { uint4 u[2]; __hip_bfloat16 hh[16]; } ob;
    #pragma unroll
    for (int i = 0; i < 16; ++i) ob.hh[i] = __float2bfloat16(o[i] * inv);
    uint4* op = (uint4*)(out + (size_t)t * 256 + h * 32 + half * 16);
    op[0] = ob.u[0];
    op[1] = ob.u[1];
}

extern "C" void kernel_launch(void* const* d_in, const int* in_sizes, int n_in,
                              void* d_out, int out_size, void* d_ws, size_t ws_size,
                              hipStream_t stream)
{
    const float* x      = (const float*)d_in[0];   // (4,56,56,256)
    const float* w_qkv  = (const float*)d_in[1];   // (256,768)
    const float* b_qkv  = (const float*)d_in[2];   // (768,)
    const float* rpb    = (const float*)d_in[3];   // (8,49)
    const float* w_proj = (const float*)d_in[4];   // (256,256)
    const float* b_proj = (const float*)d_in[5];   // (256,)
    float* out = (float*)d_out;                    // (4,56,56,256) fp32

    const int M = 12544;

    char* wsp = (char*)d_ws;
    float* qf = (float*)wsp;                      wsp += (size_t)M * 256 * 4;   // 12.85 MB
    __hip_bfloat16* kp    = (__hip_bfloat16*)wsp; wsp += (size_t)4 * 64 * 64 * 256 * 2; // 8.39 MB
    __hip_bfloat16* vp    = (__hip_bfloat16*)wsp; wsp += (size_t)4 * 64 * 64 * 256 * 2; // 8.39 MB
    __hip_bfloat16* xb    = (__hip_bfloat16*)wsp; wsp += (size_t)M * 256 * 2;
    __hip_bfloat16* attnb = (__hip_bfloat16*)wsp; wsp += (size_t)M * 256 * 2;
    __hip_bfloat16* wqkvT = (__hip_bfloat16*)wsp; wsp += (size_t)768 * 256 * 2;
    __hip_bfloat16* wprojT= (__hip_bfloat16*)wsp; wsp += (size_t)256 * 256 * 2;

    const float scale = 0.17677669529663689f;  // 32^-0.5

    // fused prep: x->bf16, both weight transposes, pad-border zero of kp/vp
    prep<<<5120, 256, 0, stream>>>(x, xb, w_qkv, wqkvT, w_proj, wprojT, kp, vp);

    // qkv = xb @ wqkvT^T + b_qkv; q fp32 scaled -> qf; k/v bf16 -> padded planes
    gemm_qkv<<<dim3(6, 98), 256, 0, stream>>>(xb, wqkvT, b_qkv, qf, kp, vp, scale);

    // attention: 3136 blocks x 64 threads, single-pass online softmax
    na2d_attn7<<<3136, 64, 0, stream>>>(qf, kp, vp, rpb, attnb);

    // out = attnb @ wprojT^T + b_proj
    gemm_proj<<<dim3(2, 98), 256, 0, stream>>>(attnb, wprojT, b_proj, out);
}

// Round 10
// 173.385 us; speedup vs baseline: 3.3450x; 1.3491x over previous
//
#include <hip/hip_runtime.h>
#include <hip/hip_bf16.h>

// Shapes (fixed): B=4, H=56, W=56, C=256, NH=8, HD=32, KS=7, PAD=3
// tokens M = 4*56*56 = 12544. Padded k/v planes: [4][64][64][256] bf16,
// interior token (y,x) at plane row y+3, col x+3; border zeroed by prep.

using frag_ab = __attribute__((ext_vector_type(8))) short;  // 8 bf16 (4 VGPRs)
using f32x4   = __attribute__((ext_vector_type(4))) float;  // 4 fp32 acc

typedef const __attribute__((address_space(1))) unsigned int* gas_u32;
typedef __attribute__((address_space(3))) unsigned int*       las_u32;

__device__ __forceinline__ void gl_lds16(const void* g, void* l) {
    // async global->LDS DMA, 16 B/lane; LDS dst = wave-uniform base + lane*16
    __builtin_amdgcn_global_load_lds((gas_u32)g, (las_u32)l, 16, 0, 0);
}

__device__ __forceinline__ float bflo(unsigned int u) { return __uint_as_float(u << 16); }
__device__ __forceinline__ float bfhi(unsigned int u) { return __uint_as_float(u & 0xffff0000u); }

// ================= fused prep =================
// blocks [0,3136):    x fp32 -> xb bf16 (float4/thread)
// blocks [3136,3904): w_qkv [256][768] -> wqkvT [768][256] bf16
// blocks [3904,4160): w_proj [256][256] -> wprojT [256][256] bf16
// blocks [4160,5120): zero the 960 border cols of each padded plane
__global__ __launch_bounds__(256) void prep(
    const float* __restrict__ x,      __hip_bfloat16* __restrict__ xb,
    const float* __restrict__ w_qkv,  __hip_bfloat16* __restrict__ wqkvT,
    const float* __restrict__ w_proj, __hip_bfloat16* __restrict__ wprojT,
    __hip_bfloat16* __restrict__ kp,  __hip_bfloat16* __restrict__ vp)
{
    const int bid = blockIdx.x;
    const int tid = threadIdx.x;
    if (bid < 3136) {
        const int i = bid * 256 + tid;            // over M*256/4 = 802816
        const float4 v = ((const float4*)x)[i];
        union { ushort4 u; __hip_bfloat16 h[4]; } o;
        o.h[0] = __float2bfloat16(v.x); o.h[1] = __float2bfloat16(v.y);
        o.h[2] = __float2bfloat16(v.z); o.h[3] = __float2bfloat16(v.w);
        ((ushort4*)xb)[i] = o.u;
    } else if (bid < 3904) {
        const int idx = (bid - 3136) * 256 + tid; // over 768*256
        const int k = idx & 255, n = idx >> 8;
        wqkvT[idx] = __float2bfloat16(w_qkv[k * 768 + n]);
    } else if (bid < 4160) {
        const int idx = (bid - 3904) * 256 + tid; // over 256*256
        const int k = idx & 255, n = idx >> 8;
        wprojT[idx] = __float2bfloat16(w_proj[k * 256 + n]);
    } else {
        const int u    = (bid - 4160) * 256 + tid;   // over 8*30720
        const int ip   = u / 30720;                  // img*2 + plane
        const int rem  = u - ip * 30720;
        const int cloc = rem >> 5;                   // 0..959 border cells
        const int q16  = rem & 31;                   // 16B chunk of 256 ch
        const int img  = ip >> 1;
        __hip_bfloat16* base = (ip & 1) ? vp : kp;
        int prow, pcol;
        if (cloc < 512) {                            // full pad rows 0-2,59-63
            const int r8 = cloc >> 6;
            prow = (r8 < 3) ? r8 : r8 + 56;
            pcol = cloc & 63;
        } else {                                     // side pads of rows 3..58
            const int c2 = cloc - 512;
            prow = 3 + (c2 >> 3);
            const int cc = c2 & 7;
            pcol = (cc < 3) ? cc : cc + 56;
        }
        *(uint4*)(base + (((size_t)(img * 64 + prow)) * 64 + pcol) * 256 + q16 * 8) =
            make_uint4(0u, 0u, 0u, 0u);
    }
}

// ================= 128x128 bf16 MFMA GEMM cores =================
// 256 thr = 4 waves; wave w owns quadrant (w>>1, w&1) as 4x4 16x16x32 frags.
// Staging in fragment order via global_load_lds: wave w DMAs A row-blocks
// 2w,2w+1 and B row-blocks 2w,2w+1 (block = 16 rows x 32 k = 64 lanes x 16 B).
#define GEMM128_BODY(EPILOGUE)                                                  \
    constexpr int K = 256;                                                      \
    __shared__ frag_ab As[8][64];   /* 8 KB */                                  \
    __shared__ frag_ab Bs[8][64];   /* 8 KB */                                  \
    const int tid  = threadIdx.x;                                               \
    const int lane = tid & 63;                                                  \
    const int w    = tid >> 6;                                                  \
    const int wm   = w >> 1, wn = w & 1;                                        \
    const int m0 = blockIdx.y * 128;                                            \
    const int n0 = blockIdx.x * 128;                                            \
    const int lrow = lane & 15;                                                 \
    const int lk   = (lane >> 4) * 8;                                           \
    const __hip_bfloat16* gA0 = A  + (size_t)(m0 + (2*w+0)*16 + lrow) * K + lk; \
    const __hip_bfloat16* gA1 = A  + (size_t)(m0 + (2*w+1)*16 + lrow) * K + lk; \
    const __hip_bfloat16* gB0 = BT + (size_t)(n0 + (2*w+0)*16 + lrow) * K + lk; \
    const __hip_bfloat16* gB1 = BT + (size_t)(n0 + (2*w+1)*16 + lrow) * K + lk; \
    f32x4 acc[4][4] = {};                                                       \
    for (int k0 = 0; k0 < K; k0 += 32) {                                        \
        gl_lds16(gA0 + k0, &As[2*w+0][0]);                                      \
        gl_lds16(gA1 + k0, &As[2*w+1][0]);                                      \
        gl_lds16(gB0 + k0, &Bs[2*w+0][0]);                                      \
        gl_lds16(gB1 + k0, &Bs[2*w+1][0]);                                      \
        __syncthreads();                                                        \
        frag_ab af[4], bf[4];                                                   \
        _Pragma("unroll")                                                       \
        for (int i = 0; i < 4; ++i) { af[i] = As[wm*4+i][lane]; bf[i] = Bs[wn*4+i][lane]; } \
        _Pragma("unroll")                                                       \
        for (int i = 0; i < 4; ++i)                                             \
            _Pragma("unroll")                                                   \
            for (int j = 0; j < 4; ++j)                                         \
                acc[i][j] = __builtin_amdgcn_mfma_f32_16x16x32_bf16(af[i], bf[j], acc[i][j], 0, 0, 0); \
        __syncthreads();                                                        \
    }                                                                           \
    const int rbase = (lane >> 4) * 4;                                          \
    const int cbase = lane & 15;                                                \
    _Pragma("unroll")                                                           \
    for (int fi = 0; fi < 4; ++fi) {                                            \
        const int rm = m0 + wm * 64 + fi * 16 + rbase;                          \
        _Pragma("unroll")                                                       \
        for (int fj = 0; fj < 4; ++fj) {                                        \
            const int cn = n0 + wn * 64 + fj * 16 + cbase;                      \
            const float bv = bias[cn];                                          \
            _Pragma("unroll")                                                   \
            for (int r = 0; r < 4; ++r) {                                       \
                const int m = rm + r;                                           \
                const float val = acc[fi][fj][r] + bv;                          \
                EPILOGUE                                                        \
            }                                                                   \
        }                                                                       \
    }

// QKV GEMM: N=768; cols 0-255 -> qf fp32 (scaled); 256-511 -> kp; 512-767 -> vp
__global__ __launch_bounds__(256) void gemm_qkv(
    const __hip_bfloat16* __restrict__ A,
    const __hip_bfloat16* __restrict__ BT,
    const float* __restrict__ bias,
    float* __restrict__ qf,
    __hip_bfloat16* __restrict__ kp,
    __hip_bfloat16* __restrict__ vp,
    float qscale)
{
    GEMM128_BODY({
        const int sel = cn >> 8;                       // 0=q,1=k,2=v (uniform/block)
        if (sel == 0) {
            qf[(size_t)m * 256 + cn] = val * qscale;
        } else {
            const int c  = cn & 255;
            const int b  = m / 3136;
            const int r2 = m % 3136;
            const int yy = r2 / 56;
            const int xx = r2 % 56;
            __hip_bfloat16* dst = (sel == 1) ? kp : vp;
            dst[(((size_t)(b * 64 + yy + 3)) * 64 + (xx + 3)) * 256 + c] =
                __float2bfloat16(val);
        }
    })
}

// proj GEMM: C fp32 [M][256] = A bf16 @ BT bf16 + bias
__global__ __launch_bounds__(256) void gemm_proj(
    const __hip_bfloat16* __restrict__ A,
    const __hip_bfloat16* __restrict__ BT,
    const float* __restrict__ bias,
    float* __restrict__ C)
{
    GEMM128_BODY({
        C[(size_t)m * 256 + cn] = val;
    })
}

// ================= neighborhood attention, single-pass online softmax =======
// ONE WAVE per block (64 thr) = 4 tokens x 8 heads x 2 half-heads; grid 3136.
// KY LOOP IS ROLLED (#pragma unroll 1): with full unroll the scheduler hoists
// all 7 iterations' staging loads (up to 280 VGPRs in flight) -> VGPR=256 +
// HBM scratch spill (measured R8: 109 MB, R9: 67 MB spill stores). Rolled,
// per-iteration liveness is ~100 VGPRs: q[16]+o[16]+gk[20]+gv[20]+lg[7]+state.
// XCD swizzle: blockIdx round-robins XCDs, so seg = (bid&7)*392 + (bid>>3)
// gives each XCD 392 contiguous segments (28 consecutive image rows, k/v
// working set ~2.2 MB < 4 MB L2) -> the 7x ky row re-reads hit L2 not HBM
// (R9 FETCH was 126 MB ~= 7x the planes).
// Per ky: stage k-row AND v-row (10 cols x 256 ch bf16) into separate LDS
// buffers (528 B col stride = 132 words == 4 mod 32 -> measured 0 conflicts
// R6-R9); v-row loads in flight during QK, next k-row during the PV update.
// Single-buffered: same-wave DS ops are in-order, so next iteration's writes
// cannot pass this iteration's reads. Zero-padded planes => branch-free; OOB
// gives logit = rpb and v = 0 (reference zero-pad softmax semantics).
__global__ __launch_bounds__(64) void na2d_attn8(
    const float* __restrict__ qf,
    const __hip_bfloat16* __restrict__ kp,
    const __hip_bfloat16* __restrict__ vp,
    const float* __restrict__ rpb,
    __hip_bfloat16* __restrict__ out)
{
    const int lane = threadIdx.x;       // 0..63
    const int half = lane & 1;          // 16-ch half of a head
    const int h    = (lane >> 1) & 7;   // head
    const int tl   = (lane >> 4) & 3;   // token within 4-token segment

    const int bid = blockIdx.x;         // 0..3135
    const int seg = (bid & 7) * 392 + (bid >> 3);   // XCD-contiguous remap
    const int row = seg / 14;           // b*56 + y
    const int x0  = (seg % 14) * 4;     // 0..52
    const int b   = row / 56;
    const int y   = row % 56;
    const int t   = row * 56 + x0 + tl;
    const int prow0 = b * 64 + y;       // padded plane row for ky=0

    __shared__ __hip_bfloat16 kbuf[10 * 264];   // 5.28 KB, col stride 528 B
    __shared__ __hip_bfloat16 vbuf[10 * 264];   // 5.28 KB
    __shared__ float srpb[8 * 49];

    for (int i = lane; i < 8 * 49; i += 64) srpb[i] = rpb[i];
    __syncthreads();                    // single-wave barrier: cheap

    // q: 16 fp32 channels (4 tokens' 256 ch are contiguous across the wave)
    float q[16];
    {
        const float4* qp = (const float4*)(qf + (size_t)t * 256 + h * 32 + half * 16);
        #pragma unroll
        for (int i = 0; i < 4; ++i) {
            const float4 v4 = qp[i];
            q[4 * i + 0] = v4.x; q[4 * i + 1] = v4.y;
            q[4 * i + 2] = v4.z; q[4 * i + 3] = v4.w;
        }
    }

    uint4 gk[5], gv[5];
    auto gload = [&](const __hip_bfloat16* plane, int ky, uint4* g) {
        const __hip_bfloat16* rb =
            plane + ((size_t)(prow0 + ky) * 64 + x0) * 256 + lane * 8;
        #pragma unroll
        for (int i = 0; i < 5; ++i) g[i] = *(const uint4*)(rb + i * 512);
    };
    auto lwrite = [&](__hip_bfloat16* buf, const uint4* g) {
        char* base = (char*)buf;
        #pragma unroll
        for (int i = 0; i < 5; ++i) {
            const int unit = lane + i * 64;     // 0..319
            const int col  = unit >> 5;         // 0..9 (token in window)
            const int j    = unit & 31;         // 16B chunk of 512 B token
            *(uint4*)(base + col * 528 + j * 16) = g[i];
        }
    };

    const float* rp = &srpb[h * 49];
    float m = -1e30f, l = 0.f;
    float o[16] = {};

    gload(kp, 0, gk);
    #pragma unroll 1
    for (int ky = 0; ky < 7; ++ky) {
        lwrite(kbuf, gk);                       // waits vmcnt for gk
        gload(vp, ky, gv);                      // v row in flight during QK
        // ---- 7 row logits from kbuf ----
        float lg[7];
        #pragma unroll
        for (int kx = 0; kx < 7; ++kx) {
            const uint4* p = (const uint4*)((const char*)kbuf +
                                            (tl + kx) * 528 + h * 64 + half * 32);
            float s = 0.f;
            #pragma unroll
            for (int qd = 0; qd < 2; ++qd) {
                const uint4 wv = p[qd];
                const int o8 = qd * 8;
                s += q[o8 + 0] * bflo(wv.x) + q[o8 + 1] * bfhi(wv.x)
                   + q[o8 + 2] * bflo(wv.y) + q[o8 + 3] * bfhi(wv.y)
                   + q[o8 + 4] * bflo(wv.z) + q[o8 + 5] * bfhi(wv.z)
                   + q[o8 + 6] * bflo(wv.w) + q[o8 + 7] * bfhi(wv.w);
            }
            lg[kx] = s;
        }
        lwrite(vbuf, gv);                       // waits vmcnt for gv
        if (ky < 6) gload(kp, ky + 1, gk);      // next k row in flight
        // ---- merge half-head partials + rpb ----
        #pragma unroll
        for (int kx = 0; kx < 7; ++kx) {
            lg[kx] += __shfl_xor(lg[kx], 1, 64);
            lg[kx] += rp[ky * 7 + kx];
        }
        // ---- online softmax update ----
        float rmax = lg[0];
        #pragma unroll
        for (int kx = 1; kx < 7; ++kx) rmax = fmaxf(rmax, lg[kx]);
        const float mnew  = fmaxf(m, rmax);
        const float alpha = __expf(m - mnew);   // ky=0: exp(-inf)=0
        m = mnew;
        l *= alpha;
        #pragma unroll
        for (int i = 0; i < 16; ++i) o[i] *= alpha;
        #pragma unroll
        for (int kx = 0; kx < 7; ++kx) {
            const float pr = __expf(lg[kx] - mnew);
            l += pr;
            const uint4* p = (const uint4*)((const char*)vbuf +
                                            (tl + kx) * 528 + h * 64 + half * 32);
            #pragma unroll
            for (int qd = 0; qd < 2; ++qd) {
                const uint4 wv = p[qd];
                const int o8 = qd * 8;
                o[o8 + 0] += pr * bflo(wv.x); o[o8 + 1] += pr * bfhi(wv.x);
                o[o8 + 2] += pr * bflo(wv.y); o[o8 + 3] += pr * bfhi(wv.y);
                o[o8 + 4] += pr * bflo(wv.z); o[o8 + 5] += pr * bfhi(wv.z);
                o[o8 + 6] += pr * bflo(wv.w); o[o8 + 7] += pr * bfhi(wv.w);
            }
        }
    }

    // ---- store bf16 (feeds proj GEMM) ----
    const float inv = 1.f / l;
    union { uint4 u[2]; __hip_bfloat16 hh[16]; } ob;
    #pragma unroll
    for (int i = 0; i < 16; ++i) ob.hh[i] = __float2bfloat16(o[i] * inv);
    uint4* op = (uint4*)(out + (size_t)t * 256 + h * 32 + half * 16);
    op[0] = ob.u[0];
    op[1] = ob.u[1];
}

extern "C" void kernel_launch(void* const* d_in, const int* in_sizes, int n_in,
                              void* d_out, int out_size, void* d_ws, size_t ws_size,
                              hipStream_t stream)
{
    const float* x      = (const float*)d_in[0];   // (4,56,56,256)
    const float* w_qkv  = (const float*)d_in[1];   // (256,768)
    const float* b_qkv  = (const float*)d_in[2];   // (768,)
    const float* rpb    = (const float*)d_in[3];   // (8,49)
    const float* w_proj = (const float*)d_in[4];   // (256,256)
    const float* b_proj = (const float*)d_in[5];   // (256,)
    float* out = (float*)d_out;                    // (4,56,56,256) fp32

    const int M = 12544;

    char* wsp = (char*)d_ws;
    float* qf = (float*)wsp;                      wsp += (size_t)M * 256 * 4;   // 12.85 MB
    __hip_bfloat16* kp    = (__hip_bfloat16*)wsp; wsp += (size_t)4 * 64 * 64 * 256 * 2; // 8.39 MB
    __hip_bfloat16* vp    = (__hip_bfloat16*)wsp; wsp += (size_t)4 * 64 * 64 * 256 * 2; // 8.39 MB
    __hip_bfloat16* xb    = (__hip_bfloat16*)wsp; wsp += (size_t)M * 256 * 2;
    __hip_bfloat16* attnb = (__hip_bfloat16*)wsp; wsp += (size_t)M * 256 * 2;
    __hip_bfloat16* wqkvT = (__hip_bfloat16*)wsp; wsp += (size_t)768 * 256 * 2;
    __hip_bfloat16* wprojT= (__hip_bfloat16*)wsp; wsp += (size_t)256 * 256 * 2;

    const float scale = 0.17677669529663689f;  // 32^-0.5

    // fused prep: x->bf16, both weight transposes, pad-border zero of kp/vp
    prep<<<5120, 256, 0, stream>>>(x, xb, w_qkv, wqkvT, w_proj, wprojT, kp, vp);

    // qkv = xb @ wqkvT^T + b_qkv; q fp32 scaled -> qf; k/v bf16 -> padded planes
    gemm_qkv<<<dim3(6, 98), 256, 0, stream>>>(xb, wqkvT, b_qkv, qf, kp, vp, scale);

    // attention: 3136 blocks x 64 threads, single-pass online softmax, rolled ky
    na2d_attn8<<<3136, 64, 0, stream>>>(qf, kp, vp, rpb, attnb);

    // out = attnb @ wprojT^T + b_proj
    gemm_proj<<<dim3(2, 98), 256, 0, stream>>>(attnb, wprojT, b_proj, out);
}

// Round 11
// 139.528 us; speedup vs baseline: 4.1567x; 1.2427x over previous
//
#include <hip/hip_runtime.h>
#include <hip/hip_bf16.h>

// Shapes (fixed): B=4, H=56, W=56, C=256, NH=8, HD=32, KS=7, PAD=3
// tokens M = 4*56*56 = 12544. Padded k/v planes: [4][64][64][256] bf16,
// interior token (y,x) at plane row y+3, col x+3; border zeroed by prep.

using frag_ab = __attribute__((ext_vector_type(8))) short;  // 8 bf16 (4 VGPRs)
using f32x4   = __attribute__((ext_vector_type(4))) float;  // 4 fp32 acc

typedef const __attribute__((address_space(1))) unsigned int* gas_u32;
typedef __attribute__((address_space(3))) unsigned int*       las_u32;

__device__ __forceinline__ void gl_lds16(const void* g, void* l) {
    // async global->LDS DMA, 16 B/lane; LDS dst = wave-uniform base + lane*16
    __builtin_amdgcn_global_load_lds((gas_u32)g, (las_u32)l, 16, 0, 0);
}

__device__ __forceinline__ float bflo(unsigned int u) { return __uint_as_float(u << 16); }
__device__ __forceinline__ float bfhi(unsigned int u) { return __uint_as_float(u & 0xffff0000u); }

// ================= fused prep =================
// blocks [0,3136):    x fp32 -> xb bf16 (float4/thread)
// blocks [3136,3904): w_qkv [256][768] -> wqkvT [768][256] bf16
// blocks [3904,4160): w_proj [256][256] -> wprojT [256][256] bf16
// blocks [4160,5120): zero the 960 border cols of each padded plane
__global__ __launch_bounds__(256) void prep(
    const float* __restrict__ x,      __hip_bfloat16* __restrict__ xb,
    const float* __restrict__ w_qkv,  __hip_bfloat16* __restrict__ wqkvT,
    const float* __restrict__ w_proj, __hip_bfloat16* __restrict__ wprojT,
    __hip_bfloat16* __restrict__ kp,  __hip_bfloat16* __restrict__ vp)
{
    const int bid = blockIdx.x;
    const int tid = threadIdx.x;
    if (bid < 3136) {
        const int i = bid * 256 + tid;            // over M*256/4 = 802816
        const float4 v = ((const float4*)x)[i];
        union { ushort4 u; __hip_bfloat16 h[4]; } o;
        o.h[0] = __float2bfloat16(v.x); o.h[1] = __float2bfloat16(v.y);
        o.h[2] = __float2bfloat16(v.z); o.h[3] = __float2bfloat16(v.w);
        ((ushort4*)xb)[i] = o.u;
    } else if (bid < 3904) {
        const int idx = (bid - 3136) * 256 + tid; // over 768*256
        const int k = idx & 255, n = idx >> 8;
        wqkvT[idx] = __float2bfloat16(w_qkv[k * 768 + n]);
    } else if (bid < 4160) {
        const int idx = (bid - 3904) * 256 + tid; // over 256*256
        const int k = idx & 255, n = idx >> 8;
        wprojT[idx] = __float2bfloat16(w_proj[k * 256 + n]);
    } else {
        const int u    = (bid - 4160) * 256 + tid;   // over 8*30720
        const int ip   = u / 30720;                  // img*2 + plane
        const int rem  = u - ip * 30720;
        const int cloc = rem >> 5;                   // 0..959 border cells
        const int q16  = rem & 31;                   // 16B chunk of 256 ch
        const int img  = ip >> 1;
        __hip_bfloat16* base = (ip & 1) ? vp : kp;
        int prow, pcol;
        if (cloc < 512) {                            // full pad rows 0-2,59-63
            const int r8 = cloc >> 6;
            prow = (r8 < 3) ? r8 : r8 + 56;
            pcol = cloc & 63;
        } else {                                     // side pads of rows 3..58
            const int c2 = cloc - 512;
            prow = 3 + (c2 >> 3);
            const int cc = c2 & 7;
            pcol = (cc < 3) ? cc : cc + 56;
        }
        *(uint4*)(base + (((size_t)(img * 64 + prow)) * 64 + pcol) * 256 + q16 * 8) =
            make_uint4(0u, 0u, 0u, 0u);
    }
}

// ================= 128x128 bf16 MFMA GEMM cores =================
// 256 thr = 4 waves; wave w owns quadrant (w>>1, w&1) as 4x4 16x16x32 frags.
// Staging in fragment order via global_load_lds: wave w DMAs A row-blocks
// 2w,2w+1 and B row-blocks 2w,2w+1 (block = 16 rows x 32 k = 64 lanes x 16 B).
#define GEMM128_BODY(EPILOGUE)                                                  \
    constexpr int K = 256;                                                      \
    __shared__ frag_ab As[8][64];   /* 8 KB */                                  \
    __shared__ frag_ab Bs[8][64];   /* 8 KB */                                  \
    const int tid  = threadIdx.x;                                               \
    const int lane = tid & 63;                                                  \
    const int w    = tid >> 6;                                                  \
    const int wm   = w >> 1, wn = w & 1;                                        \
    const int m0 = blockIdx.y * 128;                                            \
    const int n0 = blockIdx.x * 128;                                            \
    const int lrow = lane & 15;                                                 \
    const int lk   = (lane >> 4) * 8;                                           \
    const __hip_bfloat16* gA0 = A  + (size_t)(m0 + (2*w+0)*16 + lrow) * K + lk; \
    const __hip_bfloat16* gA1 = A  + (size_t)(m0 + (2*w+1)*16 + lrow) * K + lk; \
    const __hip_bfloat16* gB0 = BT + (size_t)(n0 + (2*w+0)*16 + lrow) * K + lk; \
    const __hip_bfloat16* gB1 = BT + (size_t)(n0 + (2*w+1)*16 + lrow) * K + lk; \
    f32x4 acc[4][4] = {};                                                       \
    for (int k0 = 0; k0 < K; k0 += 32) {                                        \
        gl_lds16(gA0 + k0, &As[2*w+0][0]);                                      \
        gl_lds16(gA1 + k0, &As[2*w+1][0]);                                      \
        gl_lds16(gB0 + k0, &Bs[2*w+0][0]);                                      \
        gl_lds16(gB1 + k0, &Bs[2*w+1][0]);                                      \
        __syncthreads();                                                        \
        frag_ab af[4], bf[4];                                                   \
        _Pragma("unroll")                                                       \
        for (int i = 0; i < 4; ++i) { af[i] = As[wm*4+i][lane]; bf[i] = Bs[wn*4+i][lane]; } \
        _Pragma("unroll")                                                       \
        for (int i = 0; i < 4; ++i)                                             \
            _Pragma("unroll")                                                   \
            for (int j = 0; j < 4; ++j)                                         \
                acc[i][j] = __builtin_amdgcn_mfma_f32_16x16x32_bf16(af[i], bf[j], acc[i][j], 0, 0, 0); \
        __syncthreads();                                                        \
    }                                                                           \
    const int rbase = (lane >> 4) * 4;                                          \
    const int cbase = lane & 15;                                                \
    _Pragma("unroll")                                                           \
    for (int fi = 0; fi < 4; ++fi) {                                            \
        const int rm = m0 + wm * 64 + fi * 16 + rbase;                          \
        _Pragma("unroll")                                                       \
        for (int fj = 0; fj < 4; ++fj) {                                        \
            const int cn = n0 + wn * 64 + fj * 16 + cbase;                      \
            const float bv = bias[cn];                                          \
            _Pragma("unroll")                                                   \
            for (int r = 0; r < 4; ++r) {                                       \
                const int m = rm + r;                                           \
                const float val = acc[fi][fj][r] + bv;                          \
                EPILOGUE                                                        \
            }                                                                   \
        }                                                                       \
    }

// QKV GEMM: N=768; cols 0-255 -> qf fp32 (scaled); 256-511 -> kp; 512-767 -> vp
__global__ __launch_bounds__(256) void gemm_qkv(
    const __hip_bfloat16* __restrict__ A,
    const __hip_bfloat16* __restrict__ BT,
    const float* __restrict__ bias,
    float* __restrict__ qf,
    __hip_bfloat16* __restrict__ kp,
    __hip_bfloat16* __restrict__ vp,
    float qscale)
{
    GEMM128_BODY({
        const int sel = cn >> 8;                       // 0=q,1=k,2=v (uniform/block)
        if (sel == 0) {
            qf[(size_t)m * 256 + cn] = val * qscale;
        } else {
            const int c  = cn & 255;
            const int b  = m / 3136;
            const int r2 = m % 3136;
            const int yy = r2 / 56;
            const int xx = r2 % 56;
            __hip_bfloat16* dst = (sel == 1) ? kp : vp;
            dst[(((size_t)(b * 64 + yy + 3)) * 64 + (xx + 3)) * 256 + c] =
                __float2bfloat16(val);
        }
    })
}

// proj GEMM: C fp32 [M][256] = A bf16 @ BT bf16 + bias
__global__ __launch_bounds__(256) void gemm_proj(
    const __hip_bfloat16* __restrict__ A,
    const __hip_bfloat16* __restrict__ BT,
    const float* __restrict__ bias,
    float* __restrict__ C)
{
    GEMM128_BODY({
        C[(size_t)m * 256 + cn] = val;
    })
}

// ================= neighborhood attention, single-pass online softmax =======
// ONE WAVE per block (64 thr) = 4 tokens x 8 heads x 2 half-heads; grid 3136.
// Staging registers are EXPLICIT SCALARS expanded by macro: R10's uint4 g[5]
// arrays captured by-pointer in lambdas defeated SROA -> the arrays lived in
// scratch (VGPR=68 but WRITE_SIZE=113 MB of spill evictions). Named scalars
// + rolled ky loop (#pragma unroll 1; full unroll hoists ~280 VGPRs of loads,
// measured R8/R9 -> 256-VGPR spill) keep per-iteration liveness ~100 VGPRs.
// NEVER set the launch_bounds min-waves arg here (R6: cap 84 -> 1.4 GB spill;
// R7: cap 128 -> 0.8 GB spill).
// XCD swizzle: blockIdx round-robins XCDs, so seg = (bid&7)*392 + (bid>>3)
// gives each XCD 392 contiguous segments (~2.2 MB k/v working set < 4 MB L2):
// measured FETCH 126 -> 26.6 MB (R9 -> R10).
// Per ky: stage k-row AND v-row (10 cols x 256 ch bf16) into separate LDS
// buffers, 528 B col stride (132 words == 4 mod 32 -> measured 0 conflicts
// R6-R10); v-row loads in flight during QK, next k-row during the PV update.
// Single-buffered: same-wave DS ops are in-order. Zero-padded planes =>
// branch-free; OOB gives logit = rpb and v = 0 (reference zero-pad softmax).
__global__ __launch_bounds__(64) void na2d_attn9(
    const float* __restrict__ qf,
    const __hip_bfloat16* __restrict__ kp,
    const __hip_bfloat16* __restrict__ vp,
    const float* __restrict__ rpb,
    __hip_bfloat16* __restrict__ out)
{
    const int lane = threadIdx.x;       // 0..63
    const int half = lane & 1;          // 16-ch half of a head
    const int h    = (lane >> 1) & 7;   // head
    const int tl   = (lane >> 4) & 3;   // token within 4-token segment

    const int bid = blockIdx.x;         // 0..3135
    const int seg = (bid & 7) * 392 + (bid >> 3);   // XCD-contiguous remap
    const int row = seg / 14;           // b*56 + y
    const int x0  = (seg % 14) * 4;     // 0..52
    const int b   = row / 56;
    const int y   = row % 56;
    const int t   = row * 56 + x0 + tl;
    const int prow0 = b * 64 + y;       // padded plane row for ky=0

    __shared__ __hip_bfloat16 kbuf[10 * 264];   // 5.28 KB, col stride 528 B
    __shared__ __hip_bfloat16 vbuf[10 * 264];   // 5.28 KB
    __shared__ float srpb[8 * 49];

    for (int i = lane; i < 8 * 49; i += 64) srpb[i] = rpb[i];
    __syncthreads();                    // single-wave barrier: cheap

    // q: 16 fp32 channels (4 tokens' 256 ch are contiguous across the wave)
    float q[16];
    {
        const float4* qp = (const float4*)(qf + (size_t)t * 256 + h * 32 + half * 16);
        #pragma unroll
        for (int i = 0; i < 4; ++i) {
            const float4 v4 = qp[i];
            q[4 * i + 0] = v4.x; q[4 * i + 1] = v4.y;
            q[4 * i + 2] = v4.z; q[4 * i + 3] = v4.w;
        }
    }

    // LDS write offsets: unit=lane+i*64 -> col=2i+(lane>>5), j=lane&31
    // off_i = col*528 + j*16 = wroff + i*1056
    const int wroff = (lane >> 5) * 528 + (lane & 31) * 16;
    // LDS read base for this (tl,h,half); col offsets advance by 528/kx
    const int rdoff = tl * 528 + h * 64 + half * 32;

// load one padded row segment (10 cols x 256 ch bf16 = 5 KB) into 5 scalars
#define GLOAD(plane, ky, d0, d1, d2, d3, d4)                                    \
    do {                                                                        \
        const char* rb_ = (const char*)((plane) +                               \
            ((size_t)(prow0 + (ky)) * 64 + x0) * 256 + lane * 8);               \
        d0 = *(const uint4*)(rb_);                                              \
        d1 = *(const uint4*)(rb_ + 1024);                                       \
        d2 = *(const uint4*)(rb_ + 2048);                                       \
        d3 = *(const uint4*)(rb_ + 3072);                                       \
        d4 = *(const uint4*)(rb_ + 4096);                                       \
    } while (0)

#define LWRITE(buf, s0, s1, s2, s3, s4)                                         \
    do {                                                                        \
        char* wb_ = (char*)(buf) + wroff;                                       \
        *(uint4*)(wb_)        = s0;                                             \
        *(uint4*)(wb_ + 1056) = s1;                                             \
        *(uint4*)(wb_ + 2112) = s2;                                             \
        *(uint4*)(wb_ + 3168) = s3;                                             \
        *(uint4*)(wb_ + 4224) = s4;                                             \
    } while (0)

    const float* rp = &srpb[h * 49];
    float m = -1e30f, l = 0.f;
    float o[16] = {};

    uint4 k0, k1, k2, k3, k4, v0, v1, v2, v3, v4;
    GLOAD(kp, 0, k0, k1, k2, k3, k4);

    #pragma unroll 1
    for (int ky = 0; ky < 7; ++ky) {
        LWRITE(kbuf, k0, k1, k2, k3, k4);       // waits vmcnt for k row
        GLOAD(vp, ky, v0, v1, v2, v3, v4);      // v row in flight during QK
        // ---- 7 row logits from kbuf ----
        float lg[7];
        #pragma unroll
        for (int kx = 0; kx < 7; ++kx) {
            const uint4* p = (const uint4*)((const char*)kbuf + rdoff + kx * 528);
            float s = 0.f;
            #pragma unroll
            for (int qd = 0; qd < 2; ++qd) {
                const uint4 wv = p[qd];
                const int o8 = qd * 8;
                s += q[o8 + 0] * bflo(wv.x) + q[o8 + 1] * bfhi(wv.x)
                   + q[o8 + 2] * bflo(wv.y) + q[o8 + 3] * bfhi(wv.y)
                   + q[o8 + 4] * bflo(wv.z) + q[o8 + 5] * bfhi(wv.z)
                   + q[o8 + 6] * bflo(wv.w) + q[o8 + 7] * bfhi(wv.w);
            }
            lg[kx] = s;
        }
        LWRITE(vbuf, v0, v1, v2, v3, v4);       // waits vmcnt for v row
        if (ky < 6) GLOAD(kp, ky + 1, k0, k1, k2, k3, k4);  // next k in flight
        // ---- merge half-head partials + rpb ----
        #pragma unroll
        for (int kx = 0; kx < 7; ++kx) {
            lg[kx] += __shfl_xor(lg[kx], 1, 64);
            lg[kx] += rp[ky * 7 + kx];
        }
        // ---- online softmax update ----
        float rmax = lg[0];
        #pragma unroll
        for (int kx = 1; kx < 7; ++kx) rmax = fmaxf(rmax, lg[kx]);
        const float mnew  = fmaxf(m, rmax);
        const float alpha = __expf(m - mnew);   // ky=0: exp(-inf)=0
        m = mnew;
        l *= alpha;
        #pragma unroll
        for (int i = 0; i < 16; ++i) o[i] *= alpha;
        #pragma unroll
        for (int kx = 0; kx < 7; ++kx) {
            const float pr = __expf(lg[kx] - mnew);
            l += pr;
            const uint4* p = (const uint4*)((const char*)vbuf + rdoff + kx * 528);
            #pragma unroll
            for (int qd = 0; qd < 2; ++qd) {
                const uint4 wv = p[qd];
                const int o8 = qd * 8;
                o[o8 + 0] += pr * bflo(wv.x); o[o8 + 1] += pr * bfhi(wv.x);
                o[o8 + 2] += pr * bflo(wv.y); o[o8 + 3] += pr * bfhi(wv.y);
                o[o8 + 4] += pr * bflo(wv.z); o[o8 + 5] += pr * bfhi(wv.z);
                o[o8 + 6] += pr * bflo(wv.w); o[o8 + 7] += pr * bfhi(wv.w);
            }
        }
    }
#undef GLOAD
#undef LWRITE

    // ---- store bf16 (feeds proj GEMM) ----
    const float inv = 1.f / l;
    union { uint4 u[2]; __hip_bfloat16 hh[16]; } ob;
    #pragma unroll
    for (int i = 0; i < 16; ++i) ob.hh[i] = __float2bfloat16(o[i] * inv);
    uint4* op = (uint4*)(out + (size_t)t * 256 + h * 32 + half * 16);
    op[0] = ob.u[0];
    op[1] = ob.u[1];
}

extern "C" void kernel_launch(void* const* d_in, const int* in_sizes, int n_in,
                              void* d_out, int out_size, void* d_ws, size_t ws_size,
                              hipStream_t stream)
{
    const float* x      = (const float*)d_in[0];   // (4,56,56,256)
    const float* w_qkv  = (const float*)d_in[1];   // (256,768)
    const float* b_qkv  = (const float*)d_in[2];   // (768,)
    const float* rpb    = (const float*)d_in[3];   // (8,49)
    const float* w_proj = (const float*)d_in[4];   // (256,256)
    const float* b_proj = (const float*)d_in[5];   // (256,)
    float* out = (float*)d_out;                    // (4,56,56,256) fp32

    const int M = 12544;

    char* wsp = (char*)d_ws;
    float* qf = (float*)wsp;                      wsp += (size_t)M * 256 * 4;   // 12.85 MB
    __hip_bfloat16* kp    = (__hip_bfloat16*)wsp; wsp += (size_t)4 * 64 * 64 * 256 * 2; // 8.39 MB
    __hip_bfloat16* vp    = (__hip_bfloat16*)wsp; wsp += (size_t)4 * 64 * 64 * 256 * 2; // 8.39 MB
    __hip_bfloat16* xb    = (__hip_bfloat16*)wsp; wsp += (size_t)M * 256 * 2;
    __hip_bfloat16* attnb = (__hip_bfloat16*)wsp; wsp += (size_t)M * 256 * 2;
    __hip_bfloat16* wqkvT = (__hip_bfloat16*)wsp; wsp += (size_t)768 * 256 * 2;
    __hip_bfloat16* wprojT= (__hip_bfloat16*)wsp; wsp += (size_t)256 * 256 * 2;

    const float scale = 0.17677669529663689f;  // 32^-0.5

    // fused prep: x->bf16, both weight transposes, pad-border zero of kp/vp
    prep<<<5120, 256, 0, stream>>>(x, xb, w_qkv, wqkvT, w_proj, wprojT, kp, vp);

    // qkv = xb @ wqkvT^T + b_qkv; q fp32 scaled -> qf; k/v bf16 -> padded planes
    gemm_qkv<<<dim3(6, 98), 256, 0, stream>>>(xb, wqkvT, b_qkv, qf, kp, vp, scale);

    // attention: 3136 blocks x 64 threads, single-pass online softmax, rolled ky
    na2d_attn9<<<3136, 64, 0, stream>>>(qf, kp, vp, rpb, attnb);

    // out = attnb @ wprojT^T + b_proj
    gemm_proj<<<dim3(2, 98), 256, 0, stream>>>(attnb, wprojT, b_proj, out);
}